// Round 9
// baseline (480.403 us; speedup 1.0000x reference)
//
#include <hip/hip_runtime.h>
#include <hip/hip_bf16.h>

#define NN 10000
#define NE 320000
#define HD 128
#define TILE 128
#define NTILES (NE / TILE)   // 2500 exactly

typedef __attribute__((ext_vector_type(8))) short s16x8;
typedef __attribute__((ext_vector_type(4))) short s16x4;
typedef __attribute__((ext_vector_type(4))) float f32x4;

__device__ __forceinline__ ushort f2bf(float f) {
    union { __hip_bfloat16 b; ushort u; } v;
    v.b = __float2bfloat16(f);   // HW cvt (RNE) on gfx950
    return v.u;
}
__device__ __forceinline__ float bf2f(short s) {
    union { unsigned u; float f; } v;
    v.u = ((unsigned)(unsigned short)s) << 16;
    return v.f;
}

// ---------------- CSR build (edges sorted by dst) + fused weight prep ----------------
struct WPtrs { const float* w[8]; };

__global__ void hist_kernel(const int* __restrict__ dst, int* __restrict__ cnt,
                            WPtrs p, ushort* __restrict__ wdst) {
    int e = blockIdx.x * blockDim.x + threadIdx.x;
    if (e < NE) atomicAdd(&cnt[dst[e]], 1);
    int tid = e;
    int m, idx;
    if (tid < 7 * 16384) { m = tid >> 14; idx = tid & 16383; }
    else if (tid < 7 * 16384 + 2048) { m = 7; idx = tid - 7 * 16384; }
    else return;
    int b = m >> 1, l = m & 1;
    int C = (m == 7) ? 16 : 128;
    int k = idx / C, c = idx % C;
    float v = p.w[m][k * C + c];
    wdst[l * 65536 + b * 16384 + c * 128 + k] = f2bf(v);
}

__global__ void scan_kernel(const int* __restrict__ cnt, int* __restrict__ rs, int* __restrict__ cur) {
    __shared__ int part[256];
    int t = threadIdx.x;
    const int CH = (NN + 255) / 256;  // 40
    int base = t * CH;
    int s = 0;
    for (int i = 0; i < CH; i++) {
        int idx = base + i;
        if (idx < NN) s += cnt[idx];
    }
    part[t] = s;
    __syncthreads();
    for (int off = 1; off < 256; off <<= 1) {
        int v = (t >= off) ? part[t - off] : 0;
        __syncthreads();
        part[t] += v;
        __syncthreads();
    }
    int run = part[t] - s;
    for (int i = 0; i < CH; i++) {
        int idx = base + i;
        if (idx < NN) {
            rs[idx] = run;
            cur[idx] = run;
            run += cnt[idx];
        }
    }
    if (t == 255) rs[NN] = run;
}

__global__ void scatter_kernel(const int* __restrict__ src, const int* __restrict__ dst,
                               int* __restrict__ cur, int* __restrict__ ssrc) {
    int e = blockIdx.x * blockDim.x + threadIdx.x;
    if (e < NE) {
        int p = atomicAdd(&cur[dst[e]], 1);
        ssrc[p] = src[e];
    }
}

__global__ void nodeof_kernel(const int* __restrict__ rs, int* __restrict__ nof) {
    int n = blockIdx.x * blockDim.x + threadIdx.x;
    if (n < NN) {
        int b = rs[n], e = rs[n + 1];
        for (int s = b; s < e; s++) nof[s] = n;
    }
}

// ---------------- per-node layer-1 factorization -> bf16 A/B, fused zero-fill ----------------
// 16 nodes/block, 8 nodes/thread: halves W0 load instruction count, doubles ILP.
template<int D, int ZD>
__global__ __launch_bounds__(256)
void nodeAB_kernel(const float* __restrict__ x, const float* __restrict__ W0,
                   const float* __restrict__ b0, ushort* __restrict__ A,
                   ushort* __restrict__ Bm, float* __restrict__ zbuf) {
    __shared__ float xs[16 * 128];
    int t = threadIdx.x;
    int n0 = blockIdx.x * 16;
    for (int i = t; i < 16 * D; i += 256) {
        int n = i / D, d = i % D;
        xs[n * 128 + d] = x[(size_t)(n0 + n) * D + d];
    }
    for (int i = t; i < 16 * ZD; i += 256) zbuf[(size_t)n0 * ZD + i] = 0.f;
    __syncthreads();
    int c = t & 127;
    int h = t >> 7;   // 0/1 -> nodes h*8 .. h*8+7
    float a[8], b[8];
    float bias = b0[c];
#pragma unroll
    for (int n = 0; n < 8; n++) { a[n] = bias; b[n] = 0.f; }
    for (int d = 0; d < D; d++) {
        float wt = W0[d * HD + c];
        float wb = W0[(D + d) * HD + c];
        float wd = wt - wb;
#pragma unroll
        for (int n = 0; n < 8; n++) {
            float xv = xs[(h * 8 + n) * 128 + d];
            a[n] += xv * wd;
            b[n] += xv * wb;
        }
    }
#pragma unroll
    for (int n = 0; n < 8; n++) {
        int gn = n0 + h * 8 + n;
        A[(size_t)gn * HD + c] = f2bf(a[n]);
        Bm[(size_t)gn * HD + c] = f2bf(b[n]);
    }
}

// ---------------- persistent MFMA edge kernel: weights in VGPR, single LDS buffer ----------------
// HH lifecycle per tile: h1 [e][k] -> (barrier) h2 [e][c] in-place -> (barrier) m [c][e] in-place.
// Wave w owns channel slice c in [w*32, (w+1)*32) for L2 (and c-cols for L3/agg when DOUTB=128).
// C/D frag: col = lane&15, row = (lane>>4)*4 + reg   [m89/m91 verified]
template<int DOUTB>
__global__ __launch_bounds__(256, 3)
void edge_mfma_kernel(const ushort* __restrict__ Af, const ushort* __restrict__ Bf,
                      const ushort* __restrict__ W1T, const float* __restrict__ b1,
                      const ushort* __restrict__ W2T, const float* __restrict__ b2,
                      const int* __restrict__ ssrc, const int* __restrict__ nof,
                      float* __restrict__ out) {
    __shared__ __align__(16) ushort HH[TILE * 136];    // 34816 B
    __shared__ __align__(16) ushort ALDS[32 * 136];    // 8704 B
    __shared__ __align__(16) int s_node[TILE];
    __shared__ int s_src[TILE];

    const int t = threadIdx.x;
    const int lane = t & 63;
    const int w = t >> 6;
    const int lr = lane & 15;
    const int lg = lane >> 4;

    // ---- persistent weight fragments (loaded ONCE per block) ----
    s16x8 w1f[2][4];   // c-rows w*32 + m*16 + lr
#pragma unroll
    for (int m = 0; m < 2; m++)
#pragma unroll
        for (int ks = 0; ks < 4; ks++)
            w1f[m][ks] = *(const s16x8*)(W1T + (size_t)(w * 32 + m * 16 + lr) * HD + ks * 32 + lg * 8);

    constexpr int CT3 = (DOUTB == 128) ? 2 : 1;
    s16x8 w2f[CT3][4];
#pragma unroll
    for (int ct = 0; ct < CT3; ct++) {
        const int row = (DOUTB == 128) ? ((w * 2 + ct) * 16 + lr) : lr;
#pragma unroll
        for (int ks = 0; ks < 4; ks++)
            w2f[ct][ks] = *(const s16x8*)(W2T + (size_t)row * HD + ks * 32 + lg * 8);
    }

    float bias2[2][4];
#pragma unroll
    for (int m = 0; m < 2; m++)
#pragma unroll
        for (int r = 0; r < 4; r++)
            bias2[m][r] = b1[w * 32 + m * 16 + lg * 4 + r];
    float bias3[CT3];
#pragma unroll
    for (int ct = 0; ct < CT3; ct++)
        bias3[ct] = (DOUTB == 128) ? b2[(w * 2 + ct) * 16 + lr] : b2[lr];

    for (int tile = blockIdx.x; tile < NTILES; tile += gridDim.x) {
        const int ts = tile * TILE;
        __syncthreads();   // prev tile fully consumed
        if (t < TILE) { s_node[t] = nof[ts + t]; s_src[t] = ssrc[ts + t]; }
        __syncthreads();
        const int nd0 = s_node[0];
        const int ndL = s_node[TILE - 1];

        // ---- h1 fill: HH[e][k] = bf16(relu(A[dst][k] + B[src][k])) ----
        if (ndL - nd0 < 32) {
            for (int i = t; i < (ndL - nd0 + 1) * 16; i += 256) {
                const int r = i >> 4, cg = i & 15;
                *(s16x8*)(ALDS + r * 136 + cg * 8) =
                    *(const s16x8*)(Af + (size_t)(nd0 + r) * HD + cg * 8);
            }
            __syncthreads();
            for (int i = t; i < TILE * 16; i += 256) {
                const int e = i >> 4, cg = i & 15;
                const s16x8 av = *(const s16x8*)(ALDS + (s_node[e] - nd0) * 136 + cg * 8);
                const s16x8 bv = *(const s16x8*)(Bf + (size_t)s_src[e] * HD + cg * 8);
                s16x8 hv;
#pragma unroll
                for (int j = 0; j < 8; j++)
                    hv[j] = f2bf(fmaxf(bf2f(av[j]) + bf2f(bv[j]), 0.f));
                *(s16x8*)(HH + e * 136 + cg * 8) = hv;
            }
        } else {
            for (int i = t; i < TILE * 16; i += 256) {
                const int e = i >> 4, cg = i & 15;
                const s16x8 av = *(const s16x8*)(Af + (size_t)s_node[e] * HD + cg * 8);
                const s16x8 bv = *(const s16x8*)(Bf + (size_t)s_src[e] * HD + cg * 8);
                s16x8 hv;
#pragma unroll
                for (int j = 0; j < 8; j++)
                    hv[j] = f2bf(fmaxf(bf2f(av[j]) + bf2f(bv[j]), 0.f));
                *(s16x8*)(HH + e * 136 + cg * 8) = hv;
            }
        }
        __syncthreads();

        // ---- layer 2: D[c][e], wave's 32-c slice x ALL 128 edges ----
        f32x4 acc[2][8];
#pragma unroll
        for (int m = 0; m < 2; m++)
#pragma unroll
            for (int n = 0; n < 8; n++) {
                f32x4 v; v[0] = bias2[m][0]; v[1] = bias2[m][1]; v[2] = bias2[m][2]; v[3] = bias2[m][3];
                acc[m][n] = v;
            }
#pragma unroll
        for (int ks = 0; ks < 4; ks++) {
            const int k0 = ks * 32 + lg * 8;
            s16x8 bfr[8];
#pragma unroll
            for (int n = 0; n < 8; n++)
                bfr[n] = *(const s16x8*)(HH + (n * 16 + lr) * 136 + k0);
#pragma unroll
            for (int m = 0; m < 2; m++)
#pragma unroll
                for (int n = 0; n < 8; n++)
                    acc[m][n] = __builtin_amdgcn_mfma_f32_16x16x32_bf16(w1f[m][ks], bfr[n], acc[m][n], 0, 0, 0);
        }
        __syncthreads();   // all h1 reads retired -> HH reusable

        // h2 = relu(acc) -> HH[e][c] in-place
#pragma unroll
        for (int m = 0; m < 2; m++)
#pragma unroll
            for (int n = 0; n < 8; n++) {
                const int e = n * 16 + lr;
                const int c0 = w * 32 + m * 16 + lg * 4;
                s16x4 hv;
                hv[0] = f2bf(fmaxf(acc[m][n][0], 0.f));
                hv[1] = f2bf(fmaxf(acc[m][n][1], 0.f));
                hv[2] = f2bf(fmaxf(acc[m][n][2], 0.f));
                hv[3] = f2bf(fmaxf(acc[m][n][3], 0.f));
                *(s16x4*)(HH + e * 136 + c0) = hv;
            }
        __syncthreads();   // h2 visible

        // ---- layer 3 (swapped operands): D[e][c] ----
        if constexpr (DOUTB == 128) {
            f32x4 acc3[8][2];
#pragma unroll
            for (int n = 0; n < 8; n++)
#pragma unroll
                for (int ct = 0; ct < 2; ct++) {
                    const float bb = bias3[ct];
                    f32x4 v; v[0] = bb; v[1] = bb; v[2] = bb; v[3] = bb;
                    acc3[n][ct] = v;
                }
#pragma unroll
            for (int ks = 0; ks < 4; ks++) {
                const int k0 = ks * 32 + lg * 8;
                s16x8 h2f[8];
#pragma unroll
                for (int n = 0; n < 8; n++)
                    h2f[n] = *(const s16x8*)(HH + (n * 16 + lr) * 136 + k0);
#pragma unroll
                for (int n = 0; n < 8; n++)
#pragma unroll
                    for (int ct = 0; ct < 2; ct++)
                        acc3[n][ct] = __builtin_amdgcn_mfma_f32_16x16x32_bf16(h2f[n], w2f[ct][ks], acc3[n][ct], 0, 0, 0);
            }
            __syncthreads();   // all h2 reads retired -> HH reusable as m
            // m bf16 -> HH as m[c][e]
#pragma unroll
            for (int n = 0; n < 8; n++)
#pragma unroll
                for (int ct = 0; ct < 2; ct++) {
                    const int e0 = n * 16 + lg * 4;
                    const int c = (w * 2 + ct) * 16 + lr;
                    s16x4 mv;
                    mv[0] = f2bf(acc3[n][ct][0]);
                    mv[1] = f2bf(acc3[n][ct][1]);
                    mv[2] = f2bf(acc3[n][ct][2]);
                    mv[3] = f2bf(acc3[n][ct][3]);
                    *(s16x4*)(HH + c * 136 + e0) = mv;
                }
        } else {
            // DOUTB == 16: single c-tile; waves split edges (e-tiles {2w, 2w+1})
            f32x4 acc3[2];
#pragma unroll
            for (int e2 = 0; e2 < 2; e2++) {
                const float bb = bias3[0];
                f32x4 v; v[0] = bb; v[1] = bb; v[2] = bb; v[3] = bb;
                acc3[e2] = v;
            }
#pragma unroll
            for (int ks = 0; ks < 4; ks++) {
                const int k0 = ks * 32 + lg * 8;
#pragma unroll
                for (int e2 = 0; e2 < 2; e2++) {
                    const s16x8 h2f = *(const s16x8*)(HH + ((w * 2 + e2) * 16 + lr) * 136 + k0);
                    acc3[e2] = __builtin_amdgcn_mfma_f32_16x16x32_bf16(h2f, w2f[0][ks], acc3[e2], 0, 0, 0);
                }
            }
            __syncthreads();   // h2 reads retired
#pragma unroll
            for (int e2 = 0; e2 < 2; e2++) {
                const int e0 = (w * 2 + e2) * 16 + lg * 4;
                const int c = lr;
                s16x4 mv;
                mv[0] = f2bf(acc3[e2][0]);
                mv[1] = f2bf(acc3[e2][1]);
                mv[2] = f2bf(acc3[e2][2]);
                mv[3] = f2bf(acc3[e2][3]);
                *(s16x4*)(HH + c * 136 + e0) = mv;
            }
        }
        __syncthreads();   // m visible

        // ---- aggregation via MFMA: out[slot][c] = Σ_e sel[slot][e] m[e][c] ----
        if constexpr (DOUTB == 128) {
            if (ndL - nd0 <= 15) {
                f32x4 agg[2];
                agg[0] = (f32x4)0.f; agg[1] = (f32x4)0.f;
#pragma unroll
                for (int ks = 0; ks < 4; ks++) {
                    const int4 na = *(const int4*)&s_node[ks * 32 + lg * 8];
                    const int4 nb = *(const int4*)&s_node[ks * 32 + lg * 8 + 4];
                    s16x8 sel;
                    sel[0] = (na.x - nd0 == lr) ? (short)0x3F80 : (short)0;
                    sel[1] = (na.y - nd0 == lr) ? (short)0x3F80 : (short)0;
                    sel[2] = (na.z - nd0 == lr) ? (short)0x3F80 : (short)0;
                    sel[3] = (na.w - nd0 == lr) ? (short)0x3F80 : (short)0;
                    sel[4] = (nb.x - nd0 == lr) ? (short)0x3F80 : (short)0;
                    sel[5] = (nb.y - nd0 == lr) ? (short)0x3F80 : (short)0;
                    sel[6] = (nb.z - nd0 == lr) ? (short)0x3F80 : (short)0;
                    sel[7] = (nb.w - nd0 == lr) ? (short)0x3F80 : (short)0;
#pragma unroll
                    for (int ci = 0; ci < 2; ci++) {
                        const s16x8 mf = *(const s16x8*)(HH + ((w * 2 + ci) * 16 + lr) * 136 + ks * 32 + lg * 8);
                        agg[ci] = __builtin_amdgcn_mfma_f32_16x16x32_bf16(sel, mf, agg[ci], 0, 0, 0);
                    }
                }
#pragma unroll
                for (int ci = 0; ci < 2; ci++) {
                    const int c = (w * 2 + ci) * 16 + lr;
#pragma unroll
                    for (int r = 0; r < 4; r++) {
                        const int nd = nd0 + lg * 4 + r;
                        if (nd <= ndL) {
                            float* dp = out + (size_t)nd * 128 + c;
                            const float v = agg[ci][r];
                            if (nd > nd0 && nd < ndL) *dp = v;
                            else atomicAdd(dp, v);
                        }
                    }
                }
            } else {
                for (int idx = t; idx < TILE * 128; idx += 256) {
                    const int e = idx >> 7, c = idx & 127;
                    atomicAdd(out + (size_t)s_node[e] * 128 + c, bf2f(HH[c * 136 + e]));
                }
            }
        } else {
            // DOUTB == 16: each wave aggregates its own 32-edge window
            const int nw0 = s_node[w * 32];
            const int nwL = s_node[w * 32 + 31];
            if (nwL - nw0 <= 15) {
                const int4 na = *(const int4*)&s_node[w * 32 + lg * 8];
                const int4 nb = *(const int4*)&s_node[w * 32 + lg * 8 + 4];
                s16x8 sel;
                sel[0] = (na.x - nw0 == lr) ? (short)0x3F80 : (short)0;
                sel[1] = (na.y - nw0 == lr) ? (short)0x3F80 : (short)0;
                sel[2] = (na.z - nw0 == lr) ? (short)0x3F80 : (short)0;
                sel[3] = (na.w - nw0 == lr) ? (short)0x3F80 : (short)0;
                sel[4] = (nb.x - nw0 == lr) ? (short)0x3F80 : (short)0;
                sel[5] = (nb.y - nw0 == lr) ? (short)0x3F80 : (short)0;
                sel[6] = (nb.z - nw0 == lr) ? (short)0x3F80 : (short)0;
                sel[7] = (nb.w - nw0 == lr) ? (short)0x3F80 : (short)0;
                const s16x8 mf = *(const s16x8*)(HH + lr * 136 + w * 32 + lg * 8);
                f32x4 agg = (f32x4)0.f;
                agg = __builtin_amdgcn_mfma_f32_16x16x32_bf16(sel, mf, agg, 0, 0, 0);
#pragma unroll
                for (int r = 0; r < 4; r++) {
                    const int nd = nw0 + lg * 4 + r;
                    if (nd <= nwL) {
                        float* dp = out + (size_t)nd * 16 + lr;
                        const float v = agg[r];
                        if (nd > nw0 && nd < nwL) *dp = v;
                        else atomicAdd(dp, v);
                    }
                }
            } else {
                for (int idx = lane; idx < 32 * 16; idx += 64) {
                    const int e = w * 32 + (idx >> 4), c = idx & 15;
                    atomicAdd(out + (size_t)s_node[e] * 16 + c, bf2f(HH[c * 136 + e]));
                }
            }
        }
    }
}

extern "C" void kernel_launch(void* const* d_in, const int* in_sizes, int n_in,
                              void* d_out, int out_size, void* d_ws, size_t ws_size,
                              hipStream_t stream) {
    const float* x = (const float*)d_in[0];
    const int* ei = (const int*)d_in[2];
    const int* src = ei;
    const int* dst = ei + NE;
    const float* W[4][3];
    const float* bs[4][3];
    for (int b = 0; b < 4; b++)
        for (int l = 0; l < 3; l++) {
            W[b][l]  = (const float*)d_in[4 + b * 6 + l * 2];
            bs[b][l] = (const float*)d_in[4 + b * 6 + l * 2 + 1];
        }

    float* x0   = (float*)d_ws;
    float* x1   = x0 + (size_t)NN * HD;
    ushort* A   = (ushort*)(x1 + (size_t)NN * HD);
    ushort* Bm  = A + (size_t)NN * HD;
    ushort* WT  = Bm + (size_t)NN * HD;       // 131072 ushort = 256 KB
    int* cnt    = (int*)(WT + 131072);
    int* rs     = cnt + NN;
    int* cur    = rs + NN + 1;
    int* ssrc   = cur + NN;
    int* nof    = ssrc + NE;
    float* out  = (float*)d_out;

    WPtrs wp;
    for (int b = 0; b < 4; b++) { wp.w[2 * b] = W[b][1]; wp.w[2 * b + 1] = W[b][2]; }
    hipMemsetAsync(cnt, 0, NN * sizeof(int), stream);
    hist_kernel<<<(NE + 255) / 256, 256, 0, stream>>>(dst, cnt, wp, WT);
    scan_kernel<<<1, 256, 0, stream>>>(cnt, rs, cur);
    scatter_kernel<<<(NE + 255) / 256, 256, 0, stream>>>(src, dst, cur, ssrc);
    nodeof_kernel<<<(NN + 255) / 256, 256, 0, stream>>>(rs, nof);

    const ushort* W1T[4];
    const ushort* W2T[4];
    for (int b = 0; b < 4; b++) { W1T[b] = WT + b * 16384; W2T[b] = WT + 65536 + b * 16384; }

    const int EG = 768;   // persistent, 3 blocks/CU (44.5 KB LDS), grid-stride over 2500 tiles

    // block 0 (nodeAB zeroes x0)
    nodeAB_kernel<4, 128><<<NN / 16, 256, 0, stream>>>(x, W[0][0], bs[0][0], A, Bm, x0);
    edge_mfma_kernel<128><<<EG, 256, 0, stream>>>(A, Bm, W1T[0], bs[0][1], W2T[0], bs[0][2], ssrc, nof, x0);
    // block 1 (zeroes x1)
    nodeAB_kernel<128, 128><<<NN / 16, 256, 0, stream>>>(x0, W[1][0], bs[1][0], A, Bm, x1);
    edge_mfma_kernel<128><<<EG, 256, 0, stream>>>(A, Bm, W1T[1], bs[1][1], W2T[1], bs[1][2], ssrc, nof, x1);
    // block 2 (zeroes x0)
    nodeAB_kernel<128, 128><<<NN / 16, 256, 0, stream>>>(x1, W[2][0], bs[2][0], A, Bm, x0);
    edge_mfma_kernel<128><<<EG, 256, 0, stream>>>(A, Bm, W1T[2], bs[2][1], W2T[2], bs[2][2], ssrc, nof, x0);
    // block 3 (zeroes out) -> d_out
    nodeAB_kernel<128, 16><<<NN / 16, 256, 0, stream>>>(x0, W[3][0], bs[3][0], A, Bm, out);
    edge_mfma_kernel<16><<<EG, 256, 0, stream>>>(A, Bm, W1T[3], bs[3][1], W2T[3], bs[3][2], ssrc, nof, out);
}

// Round 10
// 317.949 us; speedup vs baseline: 1.5109x; 1.5109x over previous
//
#include <hip/hip_runtime.h>
#include <hip/hip_bf16.h>

#define NN 10000
#define NE 320000
#define HD 128
#define TILE 128
#define NTILES (NE / TILE)   // 2500 exactly

typedef __attribute__((ext_vector_type(8))) short s16x8;
typedef __attribute__((ext_vector_type(4))) short s16x4;
typedef __attribute__((ext_vector_type(4))) float f32x4;

__device__ __forceinline__ ushort f2bf(float f) {
    union { __hip_bfloat16 b; ushort u; } v;
    v.b = __float2bfloat16(f);   // HW cvt (RNE) on gfx950
    return v.u;
}
__device__ __forceinline__ float bf2f(short s) {
    union { unsigned u; float f; } v;
    v.u = ((unsigned)(unsigned short)s) << 16;
    return v.f;
}

// ---------------- CSR build (edges sorted by dst) + fused weight prep ----------------
struct WPtrs { const float* w[8]; };

__global__ void hist_kernel(const int* __restrict__ dst, int* __restrict__ cnt,
                            WPtrs p, ushort* __restrict__ wdst) {
    int e = blockIdx.x * blockDim.x + threadIdx.x;
    if (e < NE) atomicAdd(&cnt[dst[e]], 1);
    int tid = e;
    int m, idx;
    if (tid < 7 * 16384) { m = tid >> 14; idx = tid & 16383; }
    else if (tid < 7 * 16384 + 2048) { m = 7; idx = tid - 7 * 16384; }
    else return;
    int b = m >> 1, l = m & 1;
    int C = (m == 7) ? 16 : 128;
    int k = idx / C, c = idx % C;
    float v = p.w[m][k * C + c];
    wdst[l * 65536 + b * 16384 + c * 128 + k] = f2bf(v);
}

__global__ void scan_kernel(const int* __restrict__ cnt, int* __restrict__ rs, int* __restrict__ cur) {
    __shared__ int part[256];
    int t = threadIdx.x;
    const int CH = (NN + 255) / 256;  // 40
    int base = t * CH;
    int s = 0;
    for (int i = 0; i < CH; i++) {
        int idx = base + i;
        if (idx < NN) s += cnt[idx];
    }
    part[t] = s;
    __syncthreads();
    for (int off = 1; off < 256; off <<= 1) {
        int v = (t >= off) ? part[t - off] : 0;
        __syncthreads();
        part[t] += v;
        __syncthreads();
    }
    int run = part[t] - s;
    for (int i = 0; i < CH; i++) {
        int idx = base + i;
        if (idx < NN) {
            rs[idx] = run;
            cur[idx] = run;
            run += cnt[idx];
        }
    }
    if (t == 255) rs[NN] = run;
}

__global__ void scatter_kernel(const int* __restrict__ src, const int* __restrict__ dst,
                               int* __restrict__ cur, int* __restrict__ ssrc) {
    int e = blockIdx.x * blockDim.x + threadIdx.x;
    if (e < NE) {
        int p = atomicAdd(&cur[dst[e]], 1);
        ssrc[p] = src[e];
    }
}

__global__ void nodeof_kernel(const int* __restrict__ rs, int* __restrict__ nof) {
    int n = blockIdx.x * blockDim.x + threadIdx.x;
    if (n < NN) {
        int b = rs[n], e = rs[n + 1];
        for (int s = b; s < e; s++) nof[s] = n;
    }
}

// ---------------- per-node layer-1 factorization -> bf16 A/B, fused zero-fill ----------------
// 16 nodes/block, 8 nodes/thread: halves W0 load instruction count, doubles ILP.
template<int D, int ZD>
__global__ __launch_bounds__(256)
void nodeAB_kernel(const float* __restrict__ x, const float* __restrict__ W0,
                   const float* __restrict__ b0, ushort* __restrict__ A,
                   ushort* __restrict__ Bm, float* __restrict__ zbuf) {
    __shared__ float xs[16 * 128];
    int t = threadIdx.x;
    int n0 = blockIdx.x * 16;
    for (int i = t; i < 16 * D; i += 256) {
        int n = i / D, d = i % D;
        xs[n * 128 + d] = x[(size_t)(n0 + n) * D + d];
    }
    for (int i = t; i < 16 * ZD; i += 256) zbuf[(size_t)n0 * ZD + i] = 0.f;
    __syncthreads();
    int c = t & 127;
    int h = t >> 7;   // 0/1 -> nodes h*8 .. h*8+7
    float a[8], b[8];
    float bias = b0[c];
#pragma unroll
    for (int n = 0; n < 8; n++) { a[n] = bias; b[n] = 0.f; }
    for (int d = 0; d < D; d++) {
        float wt = W0[d * HD + c];
        float wb = W0[(D + d) * HD + c];
        float wd = wt - wb;
#pragma unroll
        for (int n = 0; n < 8; n++) {
            float xv = xs[(h * 8 + n) * 128 + d];
            a[n] += xv * wd;
            b[n] += xv * wb;
        }
    }
#pragma unroll
    for (int n = 0; n < 8; n++) {
        int gn = n0 + h * 8 + n;
        A[(size_t)gn * HD + c] = f2bf(a[n]);
        Bm[(size_t)gn * HD + c] = f2bf(b[n]);
    }
}

// ---------------- persistent MFMA edge kernel (R8 config: 2 LDS buffers, no VGPR cap spill) ----------------
// Wave w owns channel slice c in [w*32, (w+1)*32) for L2 (and c-cols for L3/agg when DOUTB=128).
// L2:  h2[c][e] = relu(Σ_k W1T[c][k] h1[e][k])     acc[2 m-tiles][8 e-tiles]
// L3:  m[e][c]  = Σ_k h2frag[e][k] W2T[c][k]       acc3[8 e-tiles][2 c-tiles]  (swapped operands)
// AGG: out[slot][c] = Σ_e sel[slot][e] m[e][c]     (sel one-hot from s_node)
// C/D frag: col = lane&15, row = (lane>>4)*4 + reg   [m89/m91 verified]
template<int DOUTB>
__global__ __launch_bounds__(256, 2)
void edge_mfma_kernel(const ushort* __restrict__ Af, const ushort* __restrict__ Bf,
                      const ushort* __restrict__ W1T, const float* __restrict__ b1,
                      const ushort* __restrict__ W2T, const float* __restrict__ b2,
                      const int* __restrict__ ssrc, const int* __restrict__ nof,
                      float* __restrict__ out) {
    __shared__ __align__(16) ushort HH1[TILE * 136];   // h1 [e][k]; later m [c][e] bf16
    __shared__ __align__(16) ushort HH2[TILE * 136];   // h2 [e][c]
    __shared__ __align__(16) ushort ALDS[32 * 136];    // staged A rows
    __shared__ __align__(16) int s_node[TILE];
    __shared__ int s_src[TILE];

    const int t = threadIdx.x;
    const int lane = t & 63;
    const int w = t >> 6;
    const int lr = lane & 15;
    const int lg = lane >> 4;

    // ---- persistent weight fragments (loaded ONCE per block; ~5 tiles amortize) ----
    s16x8 w1f[2][4];   // c-rows w*32 + m*16 + lr
#pragma unroll
    for (int m = 0; m < 2; m++)
#pragma unroll
        for (int ks = 0; ks < 4; ks++)
            w1f[m][ks] = *(const s16x8*)(W1T + (size_t)(w * 32 + m * 16 + lr) * HD + ks * 32 + lg * 8);

    constexpr int CT3 = (DOUTB == 128) ? 2 : 1;
    s16x8 w2f[CT3][4];
#pragma unroll
    for (int ct = 0; ct < CT3; ct++) {
        const int row = (DOUTB == 128) ? ((w * 2 + ct) * 16 + lr) : lr;
#pragma unroll
        for (int ks = 0; ks < 4; ks++)
            w2f[ct][ks] = *(const s16x8*)(W2T + (size_t)row * HD + ks * 32 + lg * 8);
    }

    float bias2[2][4];
#pragma unroll
    for (int m = 0; m < 2; m++)
#pragma unroll
        for (int r = 0; r < 4; r++)
            bias2[m][r] = b1[w * 32 + m * 16 + lg * 4 + r];
    float bias3[CT3];
#pragma unroll
    for (int ct = 0; ct < CT3; ct++)
        bias3[ct] = (DOUTB == 128) ? b2[(w * 2 + ct) * 16 + lr] : b2[lr];

    for (int tile = blockIdx.x; tile < NTILES; tile += gridDim.x) {
        const int ts = tile * TILE;
        __syncthreads();   // prev iteration fully consumed
        if (t < TILE) { s_node[t] = nof[ts + t]; s_src[t] = ssrc[ts + t]; }
        __syncthreads();
        const int nd0 = s_node[0];
        const int ndL = s_node[TILE - 1];

        // ---- h1 fill: HH1[e][k] = bf16(relu(A[dst][k] + B[src][k])), row-coalesced ----
        if (ndL - nd0 < 32) {
            for (int i = t; i < (ndL - nd0 + 1) * 16; i += 256) {
                const int r = i >> 4, cg = i & 15;
                *(s16x8*)(ALDS + r * 136 + cg * 8) =
                    *(const s16x8*)(Af + (size_t)(nd0 + r) * HD + cg * 8);
            }
            __syncthreads();
            for (int i = t; i < TILE * 16; i += 256) {
                const int e = i >> 4, cg = i & 15;
                const s16x8 av = *(const s16x8*)(ALDS + (s_node[e] - nd0) * 136 + cg * 8);
                const s16x8 bv = *(const s16x8*)(Bf + (size_t)s_src[e] * HD + cg * 8);
                s16x8 hv;
#pragma unroll
                for (int j = 0; j < 8; j++)
                    hv[j] = f2bf(fmaxf(bf2f(av[j]) + bf2f(bv[j]), 0.f));
                *(s16x8*)(HH1 + e * 136 + cg * 8) = hv;
            }
        } else {
            for (int i = t; i < TILE * 16; i += 256) {
                const int e = i >> 4, cg = i & 15;
                const s16x8 av = *(const s16x8*)(Af + (size_t)s_node[e] * HD + cg * 8);
                const s16x8 bv = *(const s16x8*)(Bf + (size_t)s_src[e] * HD + cg * 8);
                s16x8 hv;
#pragma unroll
                for (int j = 0; j < 8; j++)
                    hv[j] = f2bf(fmaxf(bf2f(av[j]) + bf2f(bv[j]), 0.f));
                *(s16x8*)(HH1 + e * 136 + cg * 8) = hv;
            }
        }
        __syncthreads();

        // ---- layer 2: D[c][e], wave's 32-c slice x ALL 128 edges ----
        f32x4 acc[2][8];
#pragma unroll
        for (int m = 0; m < 2; m++)
#pragma unroll
            for (int n = 0; n < 8; n++) {
                f32x4 v; v[0] = bias2[m][0]; v[1] = bias2[m][1]; v[2] = bias2[m][2]; v[3] = bias2[m][3];
                acc[m][n] = v;
            }
#pragma unroll
        for (int ks = 0; ks < 4; ks++) {
            const int k0 = ks * 32 + lg * 8;
            s16x8 bfr[8];
#pragma unroll
            for (int n = 0; n < 8; n++)
                bfr[n] = *(const s16x8*)(HH1 + (n * 16 + lr) * 136 + k0);
#pragma unroll
            for (int m = 0; m < 2; m++)
#pragma unroll
                for (int n = 0; n < 8; n++)
                    acc[m][n] = __builtin_amdgcn_mfma_f32_16x16x32_bf16(w1f[m][ks], bfr[n], acc[m][n], 0, 0, 0);
        }
        // h2 = relu(acc) -> HH2[e][c] (separate buffer, no barrier first)
#pragma unroll
        for (int m = 0; m < 2; m++)
#pragma unroll
            for (int n = 0; n < 8; n++) {
                const int e = n * 16 + lr;
                const int c0 = w * 32 + m * 16 + lg * 4;
                s16x4 hv;
                hv[0] = f2bf(fmaxf(acc[m][n][0], 0.f));
                hv[1] = f2bf(fmaxf(acc[m][n][1], 0.f));
                hv[2] = f2bf(fmaxf(acc[m][n][2], 0.f));
                hv[3] = f2bf(fmaxf(acc[m][n][3], 0.f));
                *(s16x4*)(HH2 + e * 136 + c0) = hv;
            }
        __syncthreads();   // h2 visible; all HH1 reads retired -> HH1 free for m

        // ---- layer 3 (swapped operands): D[e][c] ----
        if constexpr (DOUTB == 128) {
            f32x4 acc3[8][2];
#pragma unroll
            for (int n = 0; n < 8; n++)
#pragma unroll
                for (int ct = 0; ct < 2; ct++) {
                    const float bb = bias3[ct];
                    f32x4 v; v[0] = bb; v[1] = bb; v[2] = bb; v[3] = bb;
                    acc3[n][ct] = v;
                }
#pragma unroll
            for (int ks = 0; ks < 4; ks++) {
                const int k0 = ks * 32 + lg * 8;
                s16x8 h2f[8];
#pragma unroll
                for (int n = 0; n < 8; n++)
                    h2f[n] = *(const s16x8*)(HH2 + (n * 16 + lr) * 136 + k0);
#pragma unroll
                for (int n = 0; n < 8; n++)
#pragma unroll
                    for (int ct = 0; ct < 2; ct++)
                        acc3[n][ct] = __builtin_amdgcn_mfma_f32_16x16x32_bf16(h2f[n], w2f[ct][ks], acc3[n][ct], 0, 0, 0);
            }
            // m bf16 -> HH1 as m[c][e]; this wave's c-cols (w*2+ct)*16+lr, all e
#pragma unroll
            for (int n = 0; n < 8; n++)
#pragma unroll
                for (int ct = 0; ct < 2; ct++) {
                    const int e0 = n * 16 + lg * 4;
                    const int c = (w * 2 + ct) * 16 + lr;
                    s16x4 mv;
                    mv[0] = f2bf(acc3[n][ct][0]);
                    mv[1] = f2bf(acc3[n][ct][1]);
                    mv[2] = f2bf(acc3[n][ct][2]);
                    mv[3] = f2bf(acc3[n][ct][3]);
                    *(s16x4*)(HH1 + c * 136 + e0) = mv;
                }
        } else {
            // DOUTB == 16: single c-tile; waves split edges (e-tiles {2w, 2w+1})
            f32x4 acc3[2];
#pragma unroll
            for (int e2 = 0; e2 < 2; e2++) {
                const float bb = bias3[0];
                f32x4 v; v[0] = bb; v[1] = bb; v[2] = bb; v[3] = bb;
                acc3[e2] = v;
            }
#pragma unroll
            for (int ks = 0; ks < 4; ks++) {
                const int k0 = ks * 32 + lg * 8;
#pragma unroll
                for (int e2 = 0; e2 < 2; e2++) {
                    const s16x8 h2f = *(const s16x8*)(HH2 + ((w * 2 + e2) * 16 + lr) * 136 + k0);
                    acc3[e2] = __builtin_amdgcn_mfma_f32_16x16x32_bf16(h2f, w2f[0][ks], acc3[e2], 0, 0, 0);
                }
            }
#pragma unroll
            for (int e2 = 0; e2 < 2; e2++) {
                const int e0 = (w * 2 + e2) * 16 + lg * 4;
                const int c = lr;
                s16x4 mv;
                mv[0] = f2bf(acc3[e2][0]);
                mv[1] = f2bf(acc3[e2][1]);
                mv[2] = f2bf(acc3[e2][2]);
                mv[3] = f2bf(acc3[e2][3]);
                *(s16x4*)(HH1 + c * 136 + e0) = mv;
            }
        }
        __syncthreads();   // m visible

        // ---- aggregation via MFMA: out[slot][c] = Σ_e sel[slot][e] m[e][c] ----
        if constexpr (DOUTB == 128) {
            if (ndL - nd0 <= 15) {
                f32x4 agg[2];
                agg[0] = (f32x4)0.f; agg[1] = (f32x4)0.f;
#pragma unroll
                for (int ks = 0; ks < 4; ks++) {
                    const int4 na = *(const int4*)&s_node[ks * 32 + lg * 8];
                    const int4 nb = *(const int4*)&s_node[ks * 32 + lg * 8 + 4];
                    s16x8 sel;
                    sel[0] = (na.x - nd0 == lr) ? (short)0x3F80 : (short)0;
                    sel[1] = (na.y - nd0 == lr) ? (short)0x3F80 : (short)0;
                    sel[2] = (na.z - nd0 == lr) ? (short)0x3F80 : (short)0;
                    sel[3] = (na.w - nd0 == lr) ? (short)0x3F80 : (short)0;
                    sel[4] = (nb.x - nd0 == lr) ? (short)0x3F80 : (short)0;
                    sel[5] = (nb.y - nd0 == lr) ? (short)0x3F80 : (short)0;
                    sel[6] = (nb.z - nd0 == lr) ? (short)0x3F80 : (short)0;
                    sel[7] = (nb.w - nd0 == lr) ? (short)0x3F80 : (short)0;
#pragma unroll
                    for (int ci = 0; ci < 2; ci++) {
                        const s16x8 mf = *(const s16x8*)(HH1 + ((w * 2 + ci) * 16 + lr) * 136 + ks * 32 + lg * 8);
                        agg[ci] = __builtin_amdgcn_mfma_f32_16x16x32_bf16(sel, mf, agg[ci], 0, 0, 0);
                    }
                }
#pragma unroll
                for (int ci = 0; ci < 2; ci++) {
                    const int c = (w * 2 + ci) * 16 + lr;
#pragma unroll
                    for (int r = 0; r < 4; r++) {
                        const int nd = nd0 + lg * 4 + r;
                        if (nd <= ndL) {
                            float* dp = out + (size_t)nd * 128 + c;
                            const float v = agg[ci][r];
                            if (nd > nd0 && nd < ndL) *dp = v;
                            else atomicAdd(dp, v);
                        }
                    }
                }
            } else {
                for (int idx = t; idx < TILE * 128; idx += 256) {
                    const int e = idx >> 7, c = idx & 127;
                    atomicAdd(out + (size_t)s_node[e] * 128 + c, bf2f(HH1[c * 136 + e]));
                }
            }
        } else {
            // DOUTB == 16: each wave aggregates its own 32-edge window
            const int nw0 = s_node[w * 32];
            const int nwL = s_node[w * 32 + 31];
            if (nwL - nw0 <= 15) {
                const int4 na = *(const int4*)&s_node[w * 32 + lg * 8];
                const int4 nb = *(const int4*)&s_node[w * 32 + lg * 8 + 4];
                s16x8 sel;
                sel[0] = (na.x - nw0 == lr) ? (short)0x3F80 : (short)0;
                sel[1] = (na.y - nw0 == lr) ? (short)0x3F80 : (short)0;
                sel[2] = (na.z - nw0 == lr) ? (short)0x3F80 : (short)0;
                sel[3] = (na.w - nw0 == lr) ? (short)0x3F80 : (short)0;
                sel[4] = (nb.x - nw0 == lr) ? (short)0x3F80 : (short)0;
                sel[5] = (nb.y - nw0 == lr) ? (short)0x3F80 : (short)0;
                sel[6] = (nb.z - nw0 == lr) ? (short)0x3F80 : (short)0;
                sel[7] = (nb.w - nw0 == lr) ? (short)0x3F80 : (short)0;
                const s16x8 mf = *(const s16x8*)(HH1 + lr * 136 + w * 32 + lg * 8);
                f32x4 agg = (f32x4)0.f;
                agg = __builtin_amdgcn_mfma_f32_16x16x32_bf16(sel, mf, agg, 0, 0, 0);
#pragma unroll
                for (int r = 0; r < 4; r++) {
                    const int nd = nw0 + lg * 4 + r;
                    if (nd <= nwL) {
                        float* dp = out + (size_t)nd * 16 + lr;
                        const float v = agg[r];
                        if (nd > nw0 && nd < nwL) *dp = v;
                        else atomicAdd(dp, v);
                    }
                }
            } else {
                for (int idx = lane; idx < 32 * 16; idx += 64) {
                    const int e = w * 32 + (idx >> 4), c = idx & 15;
                    atomicAdd(out + (size_t)s_node[e] * 16 + c, bf2f(HH1[c * 136 + e]));
                }
            }
        }
    }
}

extern "C" void kernel_launch(void* const* d_in, const int* in_sizes, int n_in,
                              void* d_out, int out_size, void* d_ws, size_t ws_size,
                              hipStream_t stream) {
    const float* x = (const float*)d_in[0];
    const int* ei = (const int*)d_in[2];
    const int* src = ei;
    const int* dst = ei + NE;
    const float* W[4][3];
    const float* bs[4][3];
    for (int b = 0; b < 4; b++)
        for (int l = 0; l < 3; l++) {
            W[b][l]  = (const float*)d_in[4 + b * 6 + l * 2];
            bs[b][l] = (const float*)d_in[4 + b * 6 + l * 2 + 1];
        }

    float* x0   = (float*)d_ws;
    float* x1   = x0 + (size_t)NN * HD;
    ushort* A   = (ushort*)(x1 + (size_t)NN * HD);
    ushort* Bm  = A + (size_t)NN * HD;
    ushort* WT  = Bm + (size_t)NN * HD;       // 131072 ushort = 256 KB
    int* cnt    = (int*)(WT + 131072);
    int* rs     = cnt + NN;
    int* cur    = rs + NN + 1;
    int* ssrc   = cur + NN;
    int* nof    = ssrc + NE;
    float* out  = (float*)d_out;

    WPtrs wp;
    for (int b = 0; b < 4; b++) { wp.w[2 * b] = W[b][1]; wp.w[2 * b + 1] = W[b][2]; }
    hipMemsetAsync(cnt, 0, NN * sizeof(int), stream);
    hist_kernel<<<(NE + 255) / 256, 256, 0, stream>>>(dst, cnt, wp, WT);
    scan_kernel<<<1, 256, 0, stream>>>(cnt, rs, cur);
    scatter_kernel<<<(NE + 255) / 256, 256, 0, stream>>>(src, dst, cur, ssrc);
    nodeof_kernel<<<(NN + 255) / 256, 256, 0, stream>>>(rs, nof);

    const ushort* W1T[4];
    const ushort* W2T[4];
    for (int b = 0; b < 4; b++) { W1T[b] = WT + b * 16384; W2T[b] = WT + 65536 + b * 16384; }

    const int EG = 512;   // persistent, 2 blocks/CU, grid-stride over 2500 tiles

    // block 0 (nodeAB zeroes x0)
    nodeAB_kernel<4, 128><<<NN / 16, 256, 0, stream>>>(x, W[0][0], bs[0][0], A, Bm, x0);
    edge_mfma_kernel<128><<<EG, 256, 0, stream>>>(A, Bm, W1T[0], bs[0][1], W2T[0], bs[0][2], ssrc, nof, x0);
    // block 1 (zeroes x1)
    nodeAB_kernel<128, 128><<<NN / 16, 256, 0, stream>>>(x0, W[1][0], bs[1][0], A, Bm, x1);
    edge_mfma_kernel<128><<<EG, 256, 0, stream>>>(A, Bm, W1T[1], bs[1][1], W2T[1], bs[1][2], ssrc, nof, x1);
    // block 2 (zeroes x0)
    nodeAB_kernel<128, 128><<<NN / 16, 256, 0, stream>>>(x1, W[2][0], bs[2][0], A, Bm, x0);
    edge_mfma_kernel<128><<<EG, 256, 0, stream>>>(A, Bm, W1T[2], bs[2][1], W2T[2], bs[2][2], ssrc, nof, x0);
    // block 3 (zeroes out) -> d_out
    nodeAB_kernel<128, 16><<<NN / 16, 256, 0, stream>>>(x0, W[3][0], bs[3][0], A, Bm, out);
    edge_mfma_kernel<16><<<EG, 256, 0, stream>>>(A, Bm, W1T[3], bs[3][1], W2T[3], bs[3][2], ssrc, nof, out);
}

// Round 11
// 266.478 us; speedup vs baseline: 1.8028x; 1.1932x over previous
//
#include <hip/hip_runtime.h>
#include <hip/hip_bf16.h>

#define NN 10000
#define NE 320000
#define HD 128
#define TILE 128
#define NTILES (NE / TILE)   // 2500 exactly

typedef __attribute__((ext_vector_type(8))) short s16x8;
typedef __attribute__((ext_vector_type(4))) short s16x4;
typedef __attribute__((ext_vector_type(4))) float f32x4;

__device__ __forceinline__ ushort f2bf(float f) {
    union { __hip_bfloat16 b; ushort u; } v;
    v.b = __float2bfloat16(f);   // HW cvt (RNE) on gfx950
    return v.u;
}
__device__ __forceinline__ float bf2f(short s) {
    union { unsigned u; float f; } v;
    v.u = ((unsigned)(unsigned short)s) << 16;
    return v.f;
}

// ---------------- CSR build (edges sorted by dst) + fused weight prep ----------------
struct WPtrs { const float* w[8]; const float* w0[3]; };

// WT layout (ushort idx): [0,65536) W1T[b][c][k]; [65536,131072) W2T[b][c][k];
// [131072, 131072+3*32768) WAB[b-1][cc][d] (cc<128: W0top-W0bot col cc; cc>=128: W0bot col cc-128)
__global__ void hist_kernel(const int* __restrict__ dst, int* __restrict__ cnt,
                            WPtrs p, ushort* __restrict__ wdst) {
    int e = blockIdx.x * blockDim.x + threadIdx.x;
    if (e < NE) atomicAdd(&cnt[dst[e]], 1);
    int tid = e;
    if (tid < 7 * 16384) {
        int m = tid >> 14, idx = tid & 16383;
        int b = m >> 1, l = m & 1;
        int k = idx / 128, c = idx % 128;
        wdst[l * 65536 + b * 16384 + c * 128 + k] = f2bf(p.w[m][k * 128 + c]);
    } else if (tid < 7 * 16384 + 2048) {
        int idx = tid - 7 * 16384;
        int k = idx / 16, c = idx % 16;
        wdst[65536 + 3 * 16384 + c * 128 + k] = f2bf(p.w[7][k * 16 + c]);
    } else if (tid < 116736 + 3 * 32768) {
        int q = tid - 116736;
        int b = q >> 15, r = q & 32767;           // b in 0..2 -> blocks 1..3
        int cc = r >> 7, d = r & 127;
        const float* w0 = p.w0[b];
        float val = (cc < 128) ? (w0[d * 128 + cc] - w0[(128 + d) * 128 + cc])
                               : w0[(128 + d) * 128 + (cc - 128)];
        wdst[131072 + b * 32768 + cc * 128 + d] = f2bf(val);
    }
}

__global__ void scan_kernel(const int* __restrict__ cnt, int* __restrict__ rs, int* __restrict__ cur) {
    __shared__ int part[256];
    int t = threadIdx.x;
    const int CH = (NN + 255) / 256;  // 40
    int base = t * CH;
    int s = 0;
    for (int i = 0; i < CH; i++) {
        int idx = base + i;
        if (idx < NN) s += cnt[idx];
    }
    part[t] = s;
    __syncthreads();
    for (int off = 1; off < 256; off <<= 1) {
        int v = (t >= off) ? part[t - off] : 0;
        __syncthreads();
        part[t] += v;
        __syncthreads();
    }
    int run = part[t] - s;
    for (int i = 0; i < CH; i++) {
        int idx = base + i;
        if (idx < NN) {
            rs[idx] = run;
            cur[idx] = run;
            run += cnt[idx];
        }
    }
    if (t == 255) rs[NN] = run;
}

__global__ void scatter_kernel(const int* __restrict__ src, const int* __restrict__ dst,
                               int* __restrict__ cur, int* __restrict__ ssrc) {
    int e = blockIdx.x * blockDim.x + threadIdx.x;
    if (e < NE) {
        int p = atomicAdd(&cur[dst[e]], 1);
        ssrc[p] = src[e];
    }
}

__global__ void nodeof_kernel(const int* __restrict__ rs, int* __restrict__ nof) {
    int n = blockIdx.x * blockDim.x + threadIdx.x;
    if (n < NN) {
        int b = rs[n], e = rs[n + 1];
        for (int s = b; s < e; s++) nof[s] = n;
    }
}

// ---------------- block-0 layer-1 (D=4, VALU is fine) ----------------
template<int D, int ZD>
__global__ __launch_bounds__(256)
void nodeAB_kernel(const float* __restrict__ x, const float* __restrict__ W0,
                   const float* __restrict__ b0, ushort* __restrict__ A,
                   ushort* __restrict__ Bm, float* __restrict__ zbuf) {
    __shared__ float xs[16 * 128];
    int t = threadIdx.x;
    int n0 = blockIdx.x * 16;
    for (int i = t; i < 16 * D; i += 256) {
        int n = i / D, d = i % D;
        xs[n * 128 + d] = x[(size_t)(n0 + n) * D + d];
    }
    for (int i = t; i < 16 * ZD; i += 256) zbuf[(size_t)n0 * ZD + i] = 0.f;
    __syncthreads();
    int c = t & 127;
    int h = t >> 7;
    float a[8], b[8];
    float bias = b0[c];
#pragma unroll
    for (int n = 0; n < 8; n++) { a[n] = bias; b[n] = 0.f; }
    for (int d = 0; d < D; d++) {
        float wt = W0[d * HD + c];
        float wb = W0[(D + d) * HD + c];
        float wd = wt - wb;
#pragma unroll
        for (int n = 0; n < 8; n++) {
            float xv = xs[(h * 8 + n) * 128 + d];
            a[n] += xv * wd;
            b[n] += xv * wb;
        }
    }
#pragma unroll
    for (int n = 0; n < 8; n++) {
        int gn = n0 + h * 8 + n;
        A[(size_t)gn * HD + c] = f2bf(a[n]);
        Bm[(size_t)gn * HD + c] = f2bf(b[n]);
    }
}

// ---------------- blocks 1-3 layer-1 via MFMA: [16 nodes] x [256 outs] x K=128 ----------------
// D[node][cc] = mfma(A=xf rows=node, B=wf rows=cc); cc<128 -> A(+bias), cc>=128 -> B.
__global__ __launch_bounds__(256)
void nodeAB_mfma_kernel(const float* __restrict__ xin, const ushort* __restrict__ WAB,
                        const float* __restrict__ b0, ushort* __restrict__ A,
                        ushort* __restrict__ Bm, float* __restrict__ zbuf, int ZD) {
    __shared__ __align__(16) ushort xs[16 * 136];
    const int t = threadIdx.x, lane = t & 63, w = t >> 6, lr = lane & 15, lg = lane >> 4;
    const int n0 = blockIdx.x * 16;

    // stage x -> bf16 LDS (16 rows x 128)
    for (int i = t; i < 512; i += 256) {
        const int n = i >> 5, s4 = i & 31;
        const float4 xv = *(const float4*)(xin + (size_t)(n0 + n) * HD + s4 * 4);
        s16x4 hx;
        hx[0] = f2bf(xv.x); hx[1] = f2bf(xv.y); hx[2] = f2bf(xv.z); hx[3] = f2bf(xv.w);
        *(s16x4*)(xs + n * 136 + s4 * 4) = hx;
    }
    for (int i = t; i < 16 * ZD; i += 256) zbuf[(size_t)n0 * ZD + i] = 0.f;
    __syncthreads();

    // weight frags: wave w covers cc in [w*64, w*64+64)
    s16x8 wf[4][4];
#pragma unroll
    for (int nt = 0; nt < 4; nt++)
#pragma unroll
        for (int ks = 0; ks < 4; ks++)
            wf[nt][ks] = *(const s16x8*)(WAB + (size_t)(w * 64 + nt * 16 + lr) * HD + ks * 32 + lg * 8);

    f32x4 acc[4];
#pragma unroll
    for (int nt = 0; nt < 4; nt++) {
        const int cc = w * 64 + nt * 16 + lr;
        const float bb = (cc < 128) ? b0[cc] : 0.f;
        f32x4 v; v[0] = bb; v[1] = bb; v[2] = bb; v[3] = bb;
        acc[nt] = v;
    }
#pragma unroll
    for (int ks = 0; ks < 4; ks++) {
        const s16x8 xf = *(const s16x8*)(xs + lr * 136 + ks * 32 + lg * 8);
#pragma unroll
        for (int nt = 0; nt < 4; nt++)
            acc[nt] = __builtin_amdgcn_mfma_f32_16x16x32_bf16(xf, wf[nt][ks], acc[nt], 0, 0, 0);
    }
    // write: row = node (lg*4+r), col = cc (lr)
#pragma unroll
    for (int nt = 0; nt < 4; nt++) {
        const int cc = w * 64 + nt * 16 + lr;
#pragma unroll
        for (int r = 0; r < 4; r++) {
            const int node = n0 + lg * 4 + r;
            const ushort val = f2bf(acc[nt][r]);
            if (cc < 128) A[(size_t)node * HD + cc] = val;
            else Bm[(size_t)node * HD + (cc - 128)] = val;
        }
    }
}

// ---------------- persistent MFMA edge kernel + cross-tile gather prefetch ----------------
// Per tile: h1 fill (av demand from L1-hot Af, bv PREFETCHED) -> L2 MFMA -> h2(HH2)
//   -> issue next bv -> L3 MFMA -> m(HH1) -> MFMA aggregation.  4 barriers/tile.
// C/D frag: col = lane&15 (B-operand row), row = (lane>>4)*4 + reg (A-operand row)  [m89/m91]
template<int DOUTB>
__global__ __launch_bounds__(256, 2)
void edge_mfma_kernel(const ushort* __restrict__ Af, const ushort* __restrict__ Bf,
                      const ushort* __restrict__ W1T, const float* __restrict__ b1,
                      const ushort* __restrict__ W2T, const float* __restrict__ b2,
                      const int* __restrict__ ssrc, const int* __restrict__ nof,
                      float* __restrict__ out) {
    __shared__ __align__(16) ushort HH1[TILE * 136];   // h1 [e][k]; later m [c][e]
    __shared__ __align__(16) ushort HH2[TILE * 136];   // h2 [e][c]
    __shared__ __align__(16) int s_node[2][TILE];

    const int t = threadIdx.x;
    const int lane = t & 63;
    const int w = t >> 6;
    const int lr = lane & 15;
    const int lg = lane >> 4;
    const int cg = t & 15;      // gather k-chunk
    const int eb = t >> 4;      // gather base edge (e_i = eb + 16*i)

    // ---- persistent weight fragments (once per block) ----
    s16x8 w1f[2][4];
#pragma unroll
    for (int m = 0; m < 2; m++)
#pragma unroll
        for (int ks = 0; ks < 4; ks++)
            w1f[m][ks] = *(const s16x8*)(W1T + (size_t)(w * 32 + m * 16 + lr) * HD + ks * 32 + lg * 8);

    constexpr int CT3 = (DOUTB == 128) ? 2 : 1;
    s16x8 w2f[CT3][4];
#pragma unroll
    for (int ct = 0; ct < CT3; ct++) {
        const int row = (DOUTB == 128) ? ((w * 2 + ct) * 16 + lr) : lr;
#pragma unroll
        for (int ks = 0; ks < 4; ks++)
            w2f[ct][ks] = *(const s16x8*)(W2T + (size_t)row * HD + ks * 32 + lg * 8);
    }

    float bias2[2][4];
#pragma unroll
    for (int m = 0; m < 2; m++)
#pragma unroll
        for (int r = 0; r < 4; r++)
            bias2[m][r] = b1[w * 32 + m * 16 + lg * 4 + r];
    float bias3[CT3];
#pragma unroll
    for (int ct = 0; ct < CT3; ct++)
        bias3[ct] = (DOUTB == 128) ? b2[(w * 2 + ct) * 16 + lr] : b2[lr];

    // ---- prologue: tile-0 indices + bv gathers ----
    int tile = blockIdx.x;
    int ts = tile * TILE;
    if (t < TILE) s_node[0][t] = nof[ts + t];
    int nd[8], sr[8];
#pragma unroll
    for (int i = 0; i < 8; i++) {
        const int e = eb + 16 * i;
        nd[i] = nof[ts + e];
        sr[i] = ssrc[ts + e];
    }
    s16x8 bv[8];
#pragma unroll
    for (int i = 0; i < 8; i++)
        bv[i] = *(const s16x8*)(Bf + (size_t)sr[i] * HD + cg * 8);
    int buf = 0;
    __syncthreads();

    for (; tile < NTILES; tile += gridDim.x) {
        ts = tile * TILE;
        const int tn = (tile + (int)gridDim.x < NTILES) ? (tile + (int)gridDim.x) : tile;
        const int tsn = tn * TILE;

        // ---- h1 fill: av on demand (dst-sorted -> L1-hot), bv prefetched ----
#pragma unroll
        for (int i = 0; i < 8; i++) {
            const int e = eb + 16 * i;
            const s16x8 av = *(const s16x8*)(Af + (size_t)nd[i] * HD + cg * 8);
            s16x8 hv;
#pragma unroll
            for (int j = 0; j < 8; j++)
                hv[j] = f2bf(fmaxf(bf2f(av[j]) + bf2f(bv[i][j]), 0.f));
            *(s16x8*)(HH1 + e * 136 + cg * 8) = hv;
        }
        __syncthreads();

        // ---- prefetch next-tile indices + s_node[buf^1] (land during L2) ----
#pragma unroll
        for (int i = 0; i < 8; i++) {
            const int e = eb + 16 * i;
            nd[i] = nof[tsn + e];
            sr[i] = ssrc[tsn + e];
        }
        if (t < TILE) s_node[buf ^ 1][t] = nof[tsn + t];

        // ---- layer 2: D[c][e], wave's 32-c slice x ALL 128 edges ----
        f32x4 acc[2][8];
#pragma unroll
        for (int m = 0; m < 2; m++)
#pragma unroll
            for (int n = 0; n < 8; n++) {
                f32x4 v; v[0] = bias2[m][0]; v[1] = bias2[m][1]; v[2] = bias2[m][2]; v[3] = bias2[m][3];
                acc[m][n] = v;
            }
#pragma unroll
        for (int ks = 0; ks < 4; ks++) {
            const int k0 = ks * 32 + lg * 8;
            s16x8 bfr[8];
#pragma unroll
            for (int n = 0; n < 8; n++)
                bfr[n] = *(const s16x8*)(HH1 + (n * 16 + lr) * 136 + k0);
#pragma unroll
            for (int m = 0; m < 2; m++)
#pragma unroll
                for (int n = 0; n < 8; n++)
                    acc[m][n] = __builtin_amdgcn_mfma_f32_16x16x32_bf16(w1f[m][ks], bfr[n], acc[m][n], 0, 0, 0);
        }
        // h2 = relu(acc) -> HH2[e][c]
#pragma unroll
        for (int m = 0; m < 2; m++)
#pragma unroll
            for (int n = 0; n < 8; n++) {
                const int e = n * 16 + lr;
                const int c0 = w * 32 + m * 16 + lg * 4;
                s16x4 hv;
                hv[0] = f2bf(fmaxf(acc[m][n][0], 0.f));
                hv[1] = f2bf(fmaxf(acc[m][n][1], 0.f));
                hv[2] = f2bf(fmaxf(acc[m][n][2], 0.f));
                hv[3] = f2bf(fmaxf(acc[m][n][3], 0.f));
                *(s16x4*)(HH2 + e * 136 + c0) = hv;
            }
        // ---- issue next-tile bv gathers (land during L3+agg) ----
#pragma unroll
        for (int i = 0; i < 8; i++)
            bv[i] = *(const s16x8*)(Bf + (size_t)sr[i] * HD + cg * 8);
        __syncthreads();   // h2 visible; all HH1 reads retired

        // ---- layer 3 (swapped operands): D[e][c]; m -> HH1 ----
        if constexpr (DOUTB == 128) {
            f32x4 acc3[8][2];
#pragma unroll
            for (int n = 0; n < 8; n++)
#pragma unroll
                for (int ct = 0; ct < 2; ct++) {
                    const float bb = bias3[ct];
                    f32x4 v; v[0] = bb; v[1] = bb; v[2] = bb; v[3] = bb;
                    acc3[n][ct] = v;
                }
#pragma unroll
            for (int ks = 0; ks < 4; ks++) {
                const int k0 = ks * 32 + lg * 8;
                s16x8 h2f[8];
#pragma unroll
                for (int n = 0; n < 8; n++)
                    h2f[n] = *(const s16x8*)(HH2 + (n * 16 + lr) * 136 + k0);
#pragma unroll
                for (int n = 0; n < 8; n++)
#pragma unroll
                    for (int ct = 0; ct < 2; ct++)
                        acc3[n][ct] = __builtin_amdgcn_mfma_f32_16x16x32_bf16(h2f[n], w2f[ct][ks], acc3[n][ct], 0, 0, 0);
            }
#pragma unroll
            for (int n = 0; n < 8; n++)
#pragma unroll
                for (int ct = 0; ct < 2; ct++) {
                    const int e0 = n * 16 + lg * 4;
                    const int c = (w * 2 + ct) * 16 + lr;
                    s16x4 mv;
                    mv[0] = f2bf(acc3[n][ct][0]);
                    mv[1] = f2bf(acc3[n][ct][1]);
                    mv[2] = f2bf(acc3[n][ct][2]);
                    mv[3] = f2bf(acc3[n][ct][3]);
                    *(s16x4*)(HH1 + c * 136 + e0) = mv;
                }
        } else {
            f32x4 acc3[2];
#pragma unroll
            for (int e2 = 0; e2 < 2; e2++) {
                const float bb = bias3[0];
                f32x4 v; v[0] = bb; v[1] = bb; v[2] = bb; v[3] = bb;
                acc3[e2] = v;
            }
#pragma unroll
            for (int ks = 0; ks < 4; ks++) {
                const int k0 = ks * 32 + lg * 8;
#pragma unroll
                for (int e2 = 0; e2 < 2; e2++) {
                    const s16x8 h2f = *(const s16x8*)(HH2 + ((w * 2 + e2) * 16 + lr) * 136 + k0);
                    acc3[e2] = __builtin_amdgcn_mfma_f32_16x16x32_bf16(h2f, w2f[0][ks], acc3[e2], 0, 0, 0);
                }
            }
#pragma unroll
            for (int e2 = 0; e2 < 2; e2++) {
                const int e0 = (w * 2 + e2) * 16 + lg * 4;
                const int c = lr;
                s16x4 mv;
                mv[0] = f2bf(acc3[e2][0]);
                mv[1] = f2bf(acc3[e2][1]);
                mv[2] = f2bf(acc3[e2][2]);
                mv[3] = f2bf(acc3[e2][3]);
                *(s16x4*)(HH1 + c * 136 + e0) = mv;
            }
        }
        __syncthreads();   // m visible

        // ---- aggregation via MFMA: out[slot][c] = Σ_e sel[slot][e] m[e][c] ----
        const int* sn = s_node[buf];
        const int nd0 = sn[0];
        const int ndL = sn[TILE - 1];
        if constexpr (DOUTB == 128) {
            if (ndL - nd0 <= 15) {
                f32x4 agg[2];
                agg[0] = (f32x4)0.f; agg[1] = (f32x4)0.f;
#pragma unroll
                for (int ks = 0; ks < 4; ks++) {
                    const int4 na = *(const int4*)&sn[ks * 32 + lg * 8];
                    const int4 nb = *(const int4*)&sn[ks * 32 + lg * 8 + 4];
                    s16x8 sel;
                    sel[0] = (na.x - nd0 == lr) ? (short)0x3F80 : (short)0;
                    sel[1] = (na.y - nd0 == lr) ? (short)0x3F80 : (short)0;
                    sel[2] = (na.z - nd0 == lr) ? (short)0x3F80 : (short)0;
                    sel[3] = (na.w - nd0 == lr) ? (short)0x3F80 : (short)0;
                    sel[4] = (nb.x - nd0 == lr) ? (short)0x3F80 : (short)0;
                    sel[5] = (nb.y - nd0 == lr) ? (short)0x3F80 : (short)0;
                    sel[6] = (nb.z - nd0 == lr) ? (short)0x3F80 : (short)0;
                    sel[7] = (nb.w - nd0 == lr) ? (short)0x3F80 : (short)0;
#pragma unroll
                    for (int ci = 0; ci < 2; ci++) {
                        const s16x8 mf = *(const s16x8*)(HH1 + ((w * 2 + ci) * 16 + lr) * 136 + ks * 32 + lg * 8);
                        agg[ci] = __builtin_amdgcn_mfma_f32_16x16x32_bf16(sel, mf, agg[ci], 0, 0, 0);
                    }
                }
#pragma unroll
                for (int ci = 0; ci < 2; ci++) {
                    const int c = (w * 2 + ci) * 16 + lr;
#pragma unroll
                    for (int r = 0; r < 4; r++) {
                        const int ndn = nd0 + lg * 4 + r;
                        if (ndn <= ndL) {
                            float* dp = out + (size_t)ndn * 128 + c;
                            const float v = agg[ci][r];
                            if (ndn > nd0 && ndn < ndL) *dp = v;
                            else atomicAdd(dp, v);
                        }
                    }
                }
            } else {
                for (int idx = t; idx < TILE * 128; idx += 256) {
                    const int e = idx >> 7, c = idx & 127;
                    atomicAdd(out + (size_t)sn[e] * 128 + c, bf2f(HH1[c * 136 + e]));
                }
            }
        } else {
            const int nw0 = sn[w * 32];
            const int nwL = sn[w * 32 + 31];
            if (nwL - nw0 <= 15) {
                const int4 na = *(const int4*)&sn[w * 32 + lg * 8];
                const int4 nb = *(const int4*)&sn[w * 32 + lg * 8 + 4];
                s16x8 sel;
                sel[0] = (na.x - nw0 == lr) ? (short)0x3F80 : (short)0;
                sel[1] = (na.y - nw0 == lr) ? (short)0x3F80 : (short)0;
                sel[2] = (na.z - nw0 == lr) ? (short)0x3F80 : (short)0;
                sel[3] = (na.w - nw0 == lr) ? (short)0x3F80 : (short)0;
                sel[4] = (nb.x - nw0 == lr) ? (short)0x3F80 : (short)0;
                sel[5] = (nb.y - nw0 == lr) ? (short)0x3F80 : (short)0;
                sel[6] = (nb.z - nw0 == lr) ? (short)0x3F80 : (short)0;
                sel[7] = (nb.w - nw0 == lr) ? (short)0x3F80 : (short)0;
                const s16x8 mf = *(const s16x8*)(HH1 + lr * 136 + w * 32 + lg * 8);
                f32x4 agg = (f32x4)0.f;
                agg = __builtin_amdgcn_mfma_f32_16x16x32_bf16(sel, mf, agg, 0, 0, 0);
#pragma unroll
                for (int r = 0; r < 4; r++) {
                    const int ndn = nw0 + lg * 4 + r;
                    if (ndn <= nwL) {
                        float* dp = out + (size_t)ndn * 16 + lr;
                        const float v = agg[r];
                        if (ndn > nw0 && ndn < nwL) *dp = v;
                        else atomicAdd(dp, v);
                    }
                }
            } else {
                for (int idx = lane; idx < 32 * 16; idx += 64) {
                    const int e = w * 32 + (idx >> 4), c = idx & 15;
                    atomicAdd(out + (size_t)sn[e] * 16 + c, bf2f(HH1[c * 136 + e]));
                }
            }
        }
        buf ^= 1;
        __syncthreads();   // agg reads retired before next h1 fill
    }
}

extern "C" void kernel_launch(void* const* d_in, const int* in_sizes, int n_in,
                              void* d_out, int out_size, void* d_ws, size_t ws_size,
                              hipStream_t stream) {
    const float* x = (const float*)d_in[0];
    const int* ei = (const int*)d_in[2];
    const int* src = ei;
    const int* dst = ei + NE;
    const float* W[4][3];
    const float* bs[4][3];
    for (int b = 0; b < 4; b++)
        for (int l = 0; l < 3; l++) {
            W[b][l]  = (const float*)d_in[4 + b * 6 + l * 2];
            bs[b][l] = (const float*)d_in[4 + b * 6 + l * 2 + 1];
        }

    float* x0   = (float*)d_ws;
    float* x1   = x0 + (size_t)NN * HD;
    ushort* A   = (ushort*)(x1 + (size_t)NN * HD);
    ushort* Bm  = A + (size_t)NN * HD;
    ushort* WT  = Bm + (size_t)NN * HD;       // 229376 ushort = 448 KB
    int* cnt    = (int*)(WT + 229376);
    int* rs     = cnt + NN;
    int* cur    = rs + NN + 1;
    int* ssrc   = cur + NN;
    int* nof    = ssrc + NE;
    float* out  = (float*)d_out;

    WPtrs wp;
    for (int b = 0; b < 4; b++) { wp.w[2 * b] = W[b][1]; wp.w[2 * b + 1] = W[b][2]; }
    for (int b = 1; b < 4; b++) wp.w0[b - 1] = W[b][0];
    hipMemsetAsync(cnt, 0, NN * sizeof(int), stream);
    hist_kernel<<<(NE + 255) / 256, 256, 0, stream>>>(dst, cnt, wp, WT);
    scan_kernel<<<1, 256, 0, stream>>>(cnt, rs, cur);
    scatter_kernel<<<(NE + 255) / 256, 256, 0, stream>>>(src, dst, cur, ssrc);
    nodeof_kernel<<<(NN + 255) / 256, 256, 0, stream>>>(rs, nof);

    const ushort* W1T[4];
    const ushort* W2T[4];
    const ushort* WAB[4];
    for (int b = 0; b < 4; b++) { W1T[b] = WT + b * 16384; W2T[b] = WT + 65536 + b * 16384; }
    for (int b = 1; b < 4; b++) WAB[b] = WT + 131072 + (b - 1) * 32768;

    const int EG = 512;   // persistent, 2 blocks/CU, grid-stride over 2500 tiles

    // block 0 (VALU layer-1, zeroes x0)
    nodeAB_kernel<4, 128><<<NN / 16, 256, 0, stream>>>(x, W[0][0], bs[0][0], A, Bm, x0);
    edge_mfma_kernel<128><<<EG, 256, 0, stream>>>(A, Bm, W1T[0], bs[0][1], W2T[0], bs[0][2], ssrc, nof, x0);
    // block 1 (MFMA layer-1, zeroes x1)
    nodeAB_mfma_kernel<<<NN / 16, 256, 0, stream>>>(x0, WAB[1], bs[1][0], A, Bm, x1, 128);
    edge_mfma_kernel<128><<<EG, 256, 0, stream>>>(A, Bm, W1T[1], bs[1][1], W2T[1], bs[1][2], ssrc, nof, x1);
    // block 2 (zeroes x0)
    nodeAB_mfma_kernel<<<NN / 16, 256, 0, stream>>>(x1, WAB[2], bs[2][0], A, Bm, x0, 128);
    edge_mfma_kernel<128><<<EG, 256, 0, stream>>>(A, Bm, W1T[2], bs[2][1], W2T[2], bs[2][2], ssrc, nof, x0);
    // block 3 (zeroes out) -> d_out
    nodeAB_mfma_kernel<<<NN / 16, 256, 0, stream>>>(x0, WAB[3], bs[3][0], A, Bm, out, 16);
    edge_mfma_kernel<16><<<EG, 256, 0, stream>>>(A, Bm, W1T[3], bs[3][1], W2T[3], bs[3][2], ssrc, nof, out);
}

// Round 12
// 264.082 us; speedup vs baseline: 1.8191x; 1.0091x over previous
//
#include <hip/hip_runtime.h>
#include <hip/hip_bf16.h>

#define NN 10000
#define NE 320000
#define HD 128
#define TILE 128
#define NTILES (NE / TILE)   // 2500 exactly

typedef __attribute__((ext_vector_type(8))) short s16x8;
typedef __attribute__((ext_vector_type(4))) short s16x4;
typedef __attribute__((ext_vector_type(4))) float f32x4;

__device__ __forceinline__ ushort f2bf(float f) {
    union { __hip_bfloat16 b; ushort u; } v;
    v.b = __float2bfloat16(f);   // HW cvt (RNE) on gfx950
    return v.u;
}
__device__ __forceinline__ float bf2f(short s) {
    union { unsigned u; float f; } v;
    v.u = ((unsigned)(unsigned short)s) << 16;
    return v.f;
}

// ---------------- CSR build (edges sorted by dst) + fused weight prep ----------------
struct WPtrs { const float* w[8]; const float* w0[3]; };

// runtime fillBuffer kernel for 40KB costs 42 us (R11 profile) -> zero via plain kernel
__global__ void zero_cnt_kernel(int* __restrict__ cnt) {
    int i = blockIdx.x * blockDim.x + threadIdx.x;
    if (i < NN) cnt[i] = 0;
}

// WT layout (ushort idx): [0,65536) W1T[b][c][k]; [65536,131072) W2T[b][c][k];
// [131072, 131072+3*32768) WAB[b-1][cc][d] (cc<128: W0top-W0bot col cc; cc>=128: W0bot col cc-128)
__global__ void hist_kernel(const int* __restrict__ dst, int* __restrict__ cnt,
                            WPtrs p, ushort* __restrict__ wdst) {
    int e = blockIdx.x * blockDim.x + threadIdx.x;
    if (e < NE) atomicAdd(&cnt[dst[e]], 1);
    int tid = e;
    if (tid < 7 * 16384) {
        int m = tid >> 14, idx = tid & 16383;
        int b = m >> 1, l = m & 1;
        int k = idx / 128, c = idx % 128;
        wdst[l * 65536 + b * 16384 + c * 128 + k] = f2bf(p.w[m][k * 128 + c]);
    } else if (tid < 7 * 16384 + 2048) {
        int idx = tid - 7 * 16384;
        int k = idx / 16, c = idx % 16;
        wdst[65536 + 3 * 16384 + c * 128 + k] = f2bf(p.w[7][k * 16 + c]);
    } else if (tid < 116736 + 3 * 32768) {
        int q = tid - 116736;
        int b = q >> 15, r = q & 32767;           // b in 0..2 -> blocks 1..3
        int cc = r >> 7, d = r & 127;
        const float* w0 = p.w0[b];
        float val = (cc < 128) ? (w0[d * 128 + cc] - w0[(128 + d) * 128 + cc])
                               : w0[(128 + d) * 128 + (cc - 128)];
        wdst[131072 + b * 32768 + cc * 128 + d] = f2bf(val);
    }
}

__global__ void scan_kernel(const int* __restrict__ cnt, int* __restrict__ rs, int* __restrict__ cur) {
    __shared__ int part[256];
    int t = threadIdx.x;
    const int CH = (NN + 255) / 256;  // 40
    int base = t * CH;
    int s = 0;
    for (int i = 0; i < CH; i++) {
        int idx = base + i;
        if (idx < NN) s += cnt[idx];
    }
    part[t] = s;
    __syncthreads();
    for (int off = 1; off < 256; off <<= 1) {
        int v = (t >= off) ? part[t - off] : 0;
        __syncthreads();
        part[t] += v;
        __syncthreads();
    }
    int run = part[t] - s;
    for (int i = 0; i < CH; i++) {
        int idx = base + i;
        if (idx < NN) {
            rs[idx] = run;
            cur[idx] = run;
            run += cnt[idx];
        }
    }
    if (t == 255) rs[NN] = run;
}

// scatter also writes nof[p] = dst[e] directly (slot's node) -> nodeof_kernel removed
__global__ void scatter_kernel(const int* __restrict__ src, const int* __restrict__ dst,
                               int* __restrict__ cur, int* __restrict__ ssrc,
                               int* __restrict__ nof) {
    int e = blockIdx.x * blockDim.x + threadIdx.x;
    if (e < NE) {
        int d = dst[e];
        int p = atomicAdd(&cur[d], 1);
        ssrc[p] = src[e];
        nof[p] = d;
    }
}

// ---------------- block-0 layer-1 (D=4, VALU is fine) ----------------
template<int D, int ZD>
__global__ __launch_bounds__(256)
void nodeAB_kernel(const float* __restrict__ x, const float* __restrict__ W0,
                   const float* __restrict__ b0, ushort* __restrict__ A,
                   ushort* __restrict__ Bm, float* __restrict__ zbuf) {
    __shared__ float xs[16 * 128];
    int t = threadIdx.x;
    int n0 = blockIdx.x * 16;
    for (int i = t; i < 16 * D; i += 256) {
        int n = i / D, d = i % D;
        xs[n * 128 + d] = x[(size_t)(n0 + n) * D + d];
    }
    for (int i = t; i < 16 * ZD; i += 256) zbuf[(size_t)n0 * ZD + i] = 0.f;
    __syncthreads();
    int c = t & 127;
    int h = t >> 7;
    float a[8], b[8];
    float bias = b0[c];
#pragma unroll
    for (int n = 0; n < 8; n++) { a[n] = bias; b[n] = 0.f; }
    for (int d = 0; d < D; d++) {
        float wt = W0[d * HD + c];
        float wb = W0[(D + d) * HD + c];
        float wd = wt - wb;
#pragma unroll
        for (int n = 0; n < 8; n++) {
            float xv = xs[(h * 8 + n) * 128 + d];
            a[n] += xv * wd;
            b[n] += xv * wb;
        }
    }
#pragma unroll
    for (int n = 0; n < 8; n++) {
        int gn = n0 + h * 8 + n;
        A[(size_t)gn * HD + c] = f2bf(a[n]);
        Bm[(size_t)gn * HD + c] = f2bf(b[n]);
    }
}

// ---------------- blocks 1-3 layer-1 via MFMA: [16 nodes] x [256 outs] x K=128 ----------------
__global__ __launch_bounds__(256)
void nodeAB_mfma_kernel(const float* __restrict__ xin, const ushort* __restrict__ WAB,
                        const float* __restrict__ b0, ushort* __restrict__ A,
                        ushort* __restrict__ Bm, float* __restrict__ zbuf, int ZD) {
    __shared__ __align__(16) ushort xs[16 * 136];
    const int t = threadIdx.x, lane = t & 63, w = t >> 6, lr = lane & 15, lg = lane >> 4;
    const int n0 = blockIdx.x * 16;

    for (int i = t; i < 512; i += 256) {
        const int n = i >> 5, s4 = i & 31;
        const float4 xv = *(const float4*)(xin + (size_t)(n0 + n) * HD + s4 * 4);
        s16x4 hx;
        hx[0] = f2bf(xv.x); hx[1] = f2bf(xv.y); hx[2] = f2bf(xv.z); hx[3] = f2bf(xv.w);
        *(s16x4*)(xs + n * 136 + s4 * 4) = hx;
    }
    for (int i = t; i < 16 * ZD; i += 256) zbuf[(size_t)n0 * ZD + i] = 0.f;
    __syncthreads();

    s16x8 wf[4][4];
#pragma unroll
    for (int nt = 0; nt < 4; nt++)
#pragma unroll
        for (int ks = 0; ks < 4; ks++)
            wf[nt][ks] = *(const s16x8*)(WAB + (size_t)(w * 64 + nt * 16 + lr) * HD + ks * 32 + lg * 8);

    f32x4 acc[4];
#pragma unroll
    for (int nt = 0; nt < 4; nt++) {
        const int cc = w * 64 + nt * 16 + lr;
        const float bb = (cc < 128) ? b0[cc] : 0.f;
        f32x4 v; v[0] = bb; v[1] = bb; v[2] = bb; v[3] = bb;
        acc[nt] = v;
    }
#pragma unroll
    for (int ks = 0; ks < 4; ks++) {
        const s16x8 xf = *(const s16x8*)(xs + lr * 136 + ks * 32 + lg * 8);
#pragma unroll
        for (int nt = 0; nt < 4; nt++)
            acc[nt] = __builtin_amdgcn_mfma_f32_16x16x32_bf16(xf, wf[nt][ks], acc[nt], 0, 0, 0);
    }
#pragma unroll
    for (int nt = 0; nt < 4; nt++) {
        const int cc = w * 64 + nt * 16 + lr;
#pragma unroll
        for (int r = 0; r < 4; r++) {
            const int node = n0 + lg * 4 + r;
            const ushort val = f2bf(acc[nt][r]);
            if (cc < 128) A[(size_t)node * HD + cc] = val;
            else Bm[(size_t)node * HD + (cc - 128)] = val;
        }
    }
}

// ---------------- persistent MFMA edge kernel + cross-tile gather prefetch ----------------
// C/D frag: col = lane&15 (B-operand row), row = (lane>>4)*4 + reg (A-operand row)  [m89/m91]
template<int DOUTB>
__global__ __launch_bounds__(256, 2)
void edge_mfma_kernel(const ushort* __restrict__ Af, const ushort* __restrict__ Bf,
                      const ushort* __restrict__ W1T, const float* __restrict__ b1,
                      const ushort* __restrict__ W2T, const float* __restrict__ b2,
                      const int* __restrict__ ssrc, const int* __restrict__ nof,
                      float* __restrict__ out) {
    __shared__ __align__(16) ushort HH1[TILE * 136];   // h1 [e][k]; later m [c][e]
    __shared__ __align__(16) ushort HH2[TILE * 136];   // h2 [e][c]
    __shared__ __align__(16) int s_node[2][TILE];

    const int t = threadIdx.x;
    const int lane = t & 63;
    const int w = t >> 6;
    const int lr = lane & 15;
    const int lg = lane >> 4;
    const int cg = t & 15;      // gather k-chunk
    const int eb = t >> 4;      // gather base edge (e_i = eb + 16*i)

    // ---- persistent weight fragments (once per block) ----
    s16x8 w1f[2][4];
#pragma unroll
    for (int m = 0; m < 2; m++)
#pragma unroll
        for (int ks = 0; ks < 4; ks++)
            w1f[m][ks] = *(const s16x8*)(W1T + (size_t)(w * 32 + m * 16 + lr) * HD + ks * 32 + lg * 8);

    constexpr int CT3 = (DOUTB == 128) ? 2 : 1;
    s16x8 w2f[CT3][4];
#pragma unroll
    for (int ct = 0; ct < CT3; ct++) {
        const int row = (DOUTB == 128) ? ((w * 2 + ct) * 16 + lr) : lr;
#pragma unroll
        for (int ks = 0; ks < 4; ks++)
            w2f[ct][ks] = *(const s16x8*)(W2T + (size_t)row * HD + ks * 32 + lg * 8);
    }

    float bias2[2][4];
#pragma unroll
    for (int m = 0; m < 2; m++)
#pragma unroll
        for (int r = 0; r < 4; r++)
            bias2[m][r] = b1[w * 32 + m * 16 + lg * 4 + r];
    float bias3[CT3];
#pragma unroll
    for (int ct = 0; ct < CT3; ct++)
        bias3[ct] = (DOUTB == 128) ? b2[(w * 2 + ct) * 16 + lr] : b2[lr];

    // ---- prologue: tile-0 indices + bv gathers ----
    int tile = blockIdx.x;
    int ts = tile * TILE;
    if (t < TILE) s_node[0][t] = nof[ts + t];
    int nd[8], sr[8];
#pragma unroll
    for (int i = 0; i < 8; i++) {
        const int e = eb + 16 * i;
        nd[i] = nof[ts + e];
        sr[i] = ssrc[ts + e];
    }
    s16x8 bv[8];
#pragma unroll
    for (int i = 0; i < 8; i++)
        bv[i] = *(const s16x8*)(Bf + (size_t)sr[i] * HD + cg * 8);
    int buf = 0;
    __syncthreads();

    for (; tile < NTILES; tile += gridDim.x) {
        ts = tile * TILE;
        const int tn = (tile + (int)gridDim.x < NTILES) ? (tile + (int)gridDim.x) : tile;
        const int tsn = tn * TILE;

        // ---- h1 fill: av on demand (dst-sorted -> L1-hot), bv prefetched ----
#pragma unroll
        for (int i = 0; i < 8; i++) {
            const int e = eb + 16 * i;
            const s16x8 av = *(const s16x8*)(Af + (size_t)nd[i] * HD + cg * 8);
            s16x8 hv;
#pragma unroll
            for (int j = 0; j < 8; j++)
                hv[j] = f2bf(fmaxf(bf2f(av[j]) + bf2f(bv[i][j]), 0.f));
            *(s16x8*)(HH1 + e * 136 + cg * 8) = hv;
        }
        __syncthreads();

        // ---- prefetch next-tile indices + s_node[buf^1] (land during L2) ----
#pragma unroll
        for (int i = 0; i < 8; i++) {
            const int e = eb + 16 * i;
            nd[i] = nof[tsn + e];
            sr[i] = ssrc[tsn + e];
        }
        if (t < TILE) s_node[buf ^ 1][t] = nof[tsn + t];

        // ---- layer 2: D[c][e], wave's 32-c slice x ALL 128 edges ----
        f32x4 acc[2][8];
#pragma unroll
        for (int m = 0; m < 2; m++)
#pragma unroll
            for (int n = 0; n < 8; n++) {
                f32x4 v; v[0] = bias2[m][0]; v[1] = bias2[m][1]; v[2] = bias2[m][2]; v[3] = bias2[m][3];
                acc[m][n] = v;
            }
#pragma unroll
        for (int ks = 0; ks < 4; ks++) {
            const int k0 = ks * 32 + lg * 8;
            s16x8 bfr[8];
#pragma unroll
            for (int n = 0; n < 8; n++)
                bfr[n] = *(const s16x8*)(HH1 + (n * 16 + lr) * 136 + k0);
#pragma unroll
            for (int m = 0; m < 2; m++)
#pragma unroll
                for (int n = 0; n < 8; n++)
                    acc[m][n] = __builtin_amdgcn_mfma_f32_16x16x32_bf16(w1f[m][ks], bfr[n], acc[m][n], 0, 0, 0);
        }
        // h2 = relu(acc) -> HH2[e][c]
#pragma unroll
        for (int m = 0; m < 2; m++)
#pragma unroll
            for (int n = 0; n < 8; n++) {
                const int e = n * 16 + lr;
                const int c0 = w * 32 + m * 16 + lg * 4;
                s16x4 hv;
                hv[0] = f2bf(fmaxf(acc[m][n][0], 0.f));
                hv[1] = f2bf(fmaxf(acc[m][n][1], 0.f));
                hv[2] = f2bf(fmaxf(acc[m][n][2], 0.f));
                hv[3] = f2bf(fmaxf(acc[m][n][3], 0.f));
                *(s16x4*)(HH2 + e * 136 + c0) = hv;
            }
        // ---- issue next-tile bv gathers (land during L3+agg) ----
#pragma unroll
        for (int i = 0; i < 8; i++)
            bv[i] = *(const s16x8*)(Bf + (size_t)sr[i] * HD + cg * 8);
        __syncthreads();   // h2 visible; all HH1 reads retired

        // ---- layer 3 (swapped operands): D[e][c]; m -> HH1 ----
        if constexpr (DOUTB == 128) {
            f32x4 acc3[8][2];
#pragma unroll
            for (int n = 0; n < 8; n++)
#pragma unroll
                for (int ct = 0; ct < 2; ct++) {
                    const float bb = bias3[ct];
                    f32x4 v; v[0] = bb; v[1] = bb; v[2] = bb; v[3] = bb;
                    acc3[n][ct] = v;
                }
#pragma unroll
            for (int ks = 0; ks < 4; ks++) {
                const int k0 = ks * 32 + lg * 8;
                s16x8 h2f[8];
#pragma unroll
                for (int n = 0; n < 8; n++)
                    h2f[n] = *(const s16x8*)(HH2 + (n * 16 + lr) * 136 + k0);
#pragma unroll
                for (int n = 0; n < 8; n++)
#pragma unroll
                    for (int ct = 0; ct < 2; ct++)
                        acc3[n][ct] = __builtin_amdgcn_mfma_f32_16x16x32_bf16(h2f[n], w2f[ct][ks], acc3[n][ct], 0, 0, 0);
            }
#pragma unroll
            for (int n = 0; n < 8; n++)
#pragma unroll
                for (int ct = 0; ct < 2; ct++) {
                    const int e0 = n * 16 + lg * 4;
                    const int c = (w * 2 + ct) * 16 + lr;
                    s16x4 mv;
                    mv[0] = f2bf(acc3[n][ct][0]);
                    mv[1] = f2bf(acc3[n][ct][1]);
                    mv[2] = f2bf(acc3[n][ct][2]);
                    mv[3] = f2bf(acc3[n][ct][3]);
                    *(s16x4*)(HH1 + c * 136 + e0) = mv;
                }
        } else {
            f32x4 acc3[2];
#pragma unroll
            for (int e2 = 0; e2 < 2; e2++) {
                const float bb = bias3[0];
                f32x4 v; v[0] = bb; v[1] = bb; v[2] = bb; v[3] = bb;
                acc3[e2] = v;
            }
#pragma unroll
            for (int ks = 0; ks < 4; ks++) {
                const int k0 = ks * 32 + lg * 8;
#pragma unroll
                for (int e2 = 0; e2 < 2; e2++) {
                    const s16x8 h2f = *(const s16x8*)(HH2 + ((w * 2 + e2) * 16 + lr) * 136 + k0);
                    acc3[e2] = __builtin_amdgcn_mfma_f32_16x16x32_bf16(h2f, w2f[0][ks], acc3[e2], 0, 0, 0);
                }
            }
#pragma unroll
            for (int e2 = 0; e2 < 2; e2++) {
                const int e0 = (w * 2 + e2) * 16 + lg * 4;
                const int c = lr;
                s16x4 mv;
                mv[0] = f2bf(acc3[e2][0]);
                mv[1] = f2bf(acc3[e2][1]);
                mv[2] = f2bf(acc3[e2][2]);
                mv[3] = f2bf(acc3[e2][3]);
                *(s16x4*)(HH1 + c * 136 + e0) = mv;
            }
        }
        __syncthreads();   // m visible

        // ---- aggregation via MFMA: out[slot][c] = Σ_e sel[slot][e] m[e][c] ----
        const int* sn = s_node[buf];
        const int nd0 = sn[0];
        const int ndL = sn[TILE - 1];
        if constexpr (DOUTB == 128) {
            if (ndL - nd0 <= 15) {
                f32x4 agg[2];
                agg[0] = (f32x4)0.f; agg[1] = (f32x4)0.f;
#pragma unroll
                for (int ks = 0; ks < 4; ks++) {
                    const int4 na = *(const int4*)&sn[ks * 32 + lg * 8];
                    const int4 nb = *(const int4*)&sn[ks * 32 + lg * 8 + 4];
                    s16x8 sel;
                    sel[0] = (na.x - nd0 == lr) ? (short)0x3F80 : (short)0;
                    sel[1] = (na.y - nd0 == lr) ? (short)0x3F80 : (short)0;
                    sel[2] = (na.z - nd0 == lr) ? (short)0x3F80 : (short)0;
                    sel[3] = (na.w - nd0 == lr) ? (short)0x3F80 : (short)0;
                    sel[4] = (nb.x - nd0 == lr) ? (short)0x3F80 : (short)0;
                    sel[5] = (nb.y - nd0 == lr) ? (short)0x3F80 : (short)0;
                    sel[6] = (nb.z - nd0 == lr) ? (short)0x3F80 : (short)0;
                    sel[7] = (nb.w - nd0 == lr) ? (short)0x3F80 : (short)0;
#pragma unroll
                    for (int ci = 0; ci < 2; ci++) {
                        const s16x8 mf = *(const s16x8*)(HH1 + ((w * 2 + ci) * 16 + lr) * 136 + ks * 32 + lg * 8);
                        agg[ci] = __builtin_amdgcn_mfma_f32_16x16x32_bf16(sel, mf, agg[ci], 0, 0, 0);
                    }
                }
#pragma unroll
                for (int ci = 0; ci < 2; ci++) {
                    const int c = (w * 2 + ci) * 16 + lr;
#pragma unroll
                    for (int r = 0; r < 4; r++) {
                        const int ndn = nd0 + lg * 4 + r;
                        if (ndn <= ndL) {
                            float* dp = out + (size_t)ndn * 128 + c;
                            const float v = agg[ci][r];
                            if (ndn > nd0 && ndn < ndL) *dp = v;
                            else atomicAdd(dp, v);
                        }
                    }
                }
            } else {
                for (int idx = t; idx < TILE * 128; idx += 256) {
                    const int e = idx >> 7, c = idx & 127;
                    atomicAdd(out + (size_t)sn[e] * 128 + c, bf2f(HH1[c * 136 + e]));
                }
            }
        } else {
            const int nw0 = sn[w * 32];
            const int nwL = sn[w * 32 + 31];
            if (nwL - nw0 <= 15) {
                const int4 na = *(const int4*)&sn[w * 32 + lg * 8];
                const int4 nb = *(const int4*)&sn[w * 32 + lg * 8 + 4];
                s16x8 sel;
                sel[0] = (na.x - nw0 == lr) ? (short)0x3F80 : (short)0;
                sel[1] = (na.y - nw0 == lr) ? (short)0x3F80 : (short)0;
                sel[2] = (na.z - nw0 == lr) ? (short)0x3F80 : (short)0;
                sel[3] = (na.w - nw0 == lr) ? (short)0x3F80 : (short)0;
                sel[4] = (nb.x - nw0 == lr) ? (short)0x3F80 : (short)0;
                sel[5] = (nb.y - nw0 == lr) ? (short)0x3F80 : (short)0;
                sel[6] = (nb.z - nw0 == lr) ? (short)0x3F80 : (short)0;
                sel[7] = (nb.w - nw0 == lr) ? (short)0x3F80 : (short)0;
                const s16x8 mf = *(const s16x8*)(HH1 + lr * 136 + w * 32 + lg * 8);
                f32x4 agg = (f32x4)0.f;
                agg = __builtin_amdgcn_mfma_f32_16x16x32_bf16(sel, mf, agg, 0, 0, 0);
#pragma unroll
                for (int r = 0; r < 4; r++) {
                    const int ndn = nw0 + lg * 4 + r;
                    if (ndn <= nwL) {
                        float* dp = out + (size_t)ndn * 16 + lr;
                        const float v = agg[r];
                        if (ndn > nw0 && ndn < nwL) *dp = v;
                        else atomicAdd(dp, v);
                    }
                }
            } else {
                for (int idx = lane; idx < 32 * 16; idx += 64) {
                    const int e = w * 32 + (idx >> 4), c = idx & 15;
                    atomicAdd(out + (size_t)sn[e] * 16 + c, bf2f(HH1[c * 136 + e]));
                }
            }
        }
        buf ^= 1;
        __syncthreads();   // agg reads retired before next h1 fill
    }
}

extern "C" void kernel_launch(void* const* d_in, const int* in_sizes, int n_in,
                              void* d_out, int out_size, void* d_ws, size_t ws_size,
                              hipStream_t stream) {
    const float* x = (const float*)d_in[0];
    const int* ei = (const int*)d_in[2];
    const int* src = ei;
    const int* dst = ei + NE;
    const float* W[4][3];
    const float* bs[4][3];
    for (int b = 0; b < 4; b++)
        for (int l = 0; l < 3; l++) {
            W[b][l]  = (const float*)d_in[4 + b * 6 + l * 2];
            bs[b][l] = (const float*)d_in[4 + b * 6 + l * 2 + 1];
        }

    float* x0   = (float*)d_ws;
    float* x1   = x0 + (size_t)NN * HD;
    ushort* A   = (ushort*)(x1 + (size_t)NN * HD);
    ushort* Bm  = A + (size_t)NN * HD;
    ushort* WT  = Bm + (size_t)NN * HD;       // 229376 ushort = 448 KB
    int* cnt    = (int*)(WT + 229376);
    int* rs     = cnt + NN;
    int* cur    = rs + NN + 1;
    int* ssrc   = cur + NN;
    int* nof    = ssrc + NE;
    float* out  = (float*)d_out;

    WPtrs wp;
    for (int b = 0; b < 4; b++) { wp.w[2 * b] = W[b][1]; wp.w[2 * b + 1] = W[b][2]; }
    for (int b = 1; b < 4; b++) wp.w0[b - 1] = W[b][0];
    zero_cnt_kernel<<<(NN + 255) / 256, 256, 0, stream>>>(cnt);
    hist_kernel<<<(NE + 255) / 256, 256, 0, stream>>>(dst, cnt, wp, WT);
    scan_kernel<<<1, 256, 0, stream>>>(cnt, rs, cur);
    scatter_kernel<<<(NE + 255) / 256, 256, 0, stream>>>(src, dst, cur, ssrc, nof);

    const ushort* W1T[4];
    const ushort* W2T[4];
    const ushort* WAB[4];
    for (int b = 0; b < 4; b++) { W1T[b] = WT + b * 16384; W2T[b] = WT + 65536 + b * 16384; }
    for (int b = 1; b < 4; b++) WAB[b] = WT + 131072 + (b - 1) * 32768;

    const int EG = 512;   // persistent, 2 blocks/CU, grid-stride over 2500 tiles

    // block 0 (VALU layer-1, zeroes x0)
    nodeAB_kernel<4, 128><<<NN / 16, 256, 0, stream>>>(x, W[0][0], bs[0][0], A, Bm, x0);
    edge_mfma_kernel<128><<<EG, 256, 0, stream>>>(A, Bm, W1T[0], bs[0][1], W2T[0], bs[0][2], ssrc, nof, x0);
    // block 1 (MFMA layer-1, zeroes x1)
    nodeAB_mfma_kernel<<<NN / 16, 256, 0, stream>>>(x0, WAB[1], bs[1][0], A, Bm, x1, 128);
    edge_mfma_kernel<128><<<EG, 256, 0, stream>>>(A, Bm, W1T[1], bs[1][1], W2T[1], bs[1][2], ssrc, nof, x1);
    // block 2 (zeroes x0)
    nodeAB_mfma_kernel<<<NN / 16, 256, 0, stream>>>(x1, WAB[2], bs[2][0], A, Bm, x0, 128);
    edge_mfma_kernel<128><<<EG, 256, 0, stream>>>(A, Bm, W1T[2], bs[2][1], W2T[2], bs[2][2], ssrc, nof, x0);
    // block 3 (zeroes out) -> d_out
    nodeAB_mfma_kernel<<<NN / 16, 256, 0, stream>>>(x0, WAB[3], bs[3][0], A, Bm, out, 16);
    edge_mfma_kernel<16><<<EG, 256, 0, stream>>>(A, Bm, W1T[3], bs[3][1], W2T[3], bs[3][2], ssrc, nof, out);
}

// Round 13
// 259.182 us; speedup vs baseline: 1.8535x; 1.0189x over previous
//
#include <hip/hip_runtime.h>
#include <hip/hip_bf16.h>

#define NN 10000
#define NE 320000
#define HD 128
#define TILE 128
#define NTILES (NE / TILE)   // 2500 exactly

typedef __attribute__((ext_vector_type(8))) short s16x8;
typedef __attribute__((ext_vector_type(4))) short s16x4;
typedef __attribute__((ext_vector_type(4))) float f32x4;

__device__ __forceinline__ ushort f2bf(float f) {
    union { __hip_bfloat16 b; ushort u; } v;
    v.b = __float2bfloat16(f);   // HW cvt (RNE) on gfx950
    return v.u;
}
__device__ __forceinline__ float bf2f(short s) {
    union { unsigned u; float f; } v;
    v.u = ((unsigned)(unsigned short)s) << 16;
    return v.f;
}

struct WPtrs { const float* w[8]; const float* w0[3]; };

// ---------------- fused prep: nodeAB block-0 + weight prep + cnt zero ----------------
// blocks [0,625): nodeAB block-0 (D=4) + zero x0
// blocks [625,1465): weight transpose/bf16 (tid-based, 840*256 = 215040 items)
// blocks [1465,1505): zero cnt
__global__ __launch_bounds__(256)
void prep_kernel(const float* __restrict__ x, const float* __restrict__ W00,
                 const float* __restrict__ b00, ushort* __restrict__ A,
                 ushort* __restrict__ Bm, float* __restrict__ x0,
                 WPtrs p, ushort* __restrict__ wdst, int* __restrict__ cnt) {
    __shared__ float xs[16 * 128];
    const int blk = blockIdx.x;
    const int t = threadIdx.x;
    if (blk < 625) {
        const int n0 = blk * 16;
        for (int i = t; i < 16 * 4; i += 256) {
            int n = i / 4, d = i % 4;
            xs[n * 128 + d] = x[(size_t)(n0 + n) * 4 + d];
        }
        for (int i = t; i < 16 * 128; i += 256) x0[(size_t)n0 * 128 + i] = 0.f;
        __syncthreads();
        int c = t & 127;
        int h = t >> 7;
        float a[8], b[8];
        float bias = b00[c];
#pragma unroll
        for (int n = 0; n < 8; n++) { a[n] = bias; b[n] = 0.f; }
#pragma unroll
        for (int d = 0; d < 4; d++) {
            float wt = W00[d * HD + c];
            float wb = W00[(4 + d) * HD + c];
            float wd = wt - wb;
#pragma unroll
            for (int n = 0; n < 8; n++) {
                float xv = xs[(h * 8 + n) * 128 + d];
                a[n] += xv * wd;
                b[n] += xv * wb;
            }
        }
#pragma unroll
        for (int n = 0; n < 8; n++) {
            int gn = n0 + h * 8 + n;
            A[(size_t)gn * HD + c] = f2bf(a[n]);
            Bm[(size_t)gn * HD + c] = f2bf(b[n]);
        }
    } else if (blk < 1465) {
        // WT layout (ushort idx): [0,65536) W1T[b][c][k]; [65536,131072) W2T[b][c][k];
        // [131072,+3*32768) WAB[b-1][cc][d]
        int tid = (blk - 625) * 256 + t;
        if (tid < 7 * 16384) {
            int m = tid >> 14, idx = tid & 16383;
            int b = m >> 1, l = m & 1;
            int k = idx / 128, c = idx % 128;
            wdst[l * 65536 + b * 16384 + c * 128 + k] = f2bf(p.w[m][k * 128 + c]);
        } else if (tid < 7 * 16384 + 2048) {
            int idx = tid - 7 * 16384;
            int k = idx / 16, c = idx % 16;
            wdst[65536 + 3 * 16384 + c * 128 + k] = f2bf(p.w[7][k * 16 + c]);
        } else {
            int q = tid - 116736;
            int b = q >> 15, r = q & 32767;           // b in 0..2 -> blocks 1..3
            int cc = r >> 7, d = r & 127;
            const float* w0 = p.w0[b];
            float val = (cc < 128) ? (w0[d * 128 + cc] - w0[(128 + d) * 128 + cc])
                                   : w0[(128 + d) * 128 + (cc - 128)];
            wdst[131072 + b * 32768 + cc * 128 + d] = f2bf(val);
        }
    } else {
        int i = (blk - 1465) * 256 + t;
        if (i < NN) cnt[i] = 0;
    }
}

// ---------------- CSR build (edges sorted by dst) ----------------
__global__ void hist_kernel(const int* __restrict__ dst, int* __restrict__ cnt) {
    int e = blockIdx.x * blockDim.x + threadIdx.x;
    if (e < NE) atomicAdd(&cnt[dst[e]], 1);
}

__global__ void scan_kernel(const int* __restrict__ cnt, int* __restrict__ rs, int* __restrict__ cur) {
    __shared__ int part[256];
    int t = threadIdx.x;
    const int CH = (NN + 255) / 256;  // 40
    int base = t * CH;
    int s = 0;
    for (int i = 0; i < CH; i++) {
        int idx = base + i;
        if (idx < NN) s += cnt[idx];
    }
    part[t] = s;
    __syncthreads();
    for (int off = 1; off < 256; off <<= 1) {
        int v = (t >= off) ? part[t - off] : 0;
        __syncthreads();
        part[t] += v;
        __syncthreads();
    }
    int run = part[t] - s;
    for (int i = 0; i < CH; i++) {
        int idx = base + i;
        if (idx < NN) {
            rs[idx] = run;
            cur[idx] = run;
            run += cnt[idx];
        }
    }
    if (t == 255) rs[NN] = run;
}

__global__ void scatter_kernel(const int* __restrict__ src, const int* __restrict__ dst,
                               int* __restrict__ cur, int* __restrict__ ssrc,
                               int* __restrict__ nof) {
    int e = blockIdx.x * blockDim.x + threadIdx.x;
    if (e < NE) {
        int d = dst[e];
        int p = atomicAdd(&cur[d], 1);
        ssrc[p] = src[e];
        nof[p] = d;
    }
}

// ---------------- blocks 1-3 layer-1 via MFMA: 32 nodes/block x 256 outs x K=128 ----------------
__global__ __launch_bounds__(256)
void nodeAB_mfma_kernel(const float* __restrict__ xin, const ushort* __restrict__ WAB,
                        const float* __restrict__ b0, ushort* __restrict__ A,
                        ushort* __restrict__ Bm, float* __restrict__ zbuf, int ZD) {
    __shared__ __align__(16) ushort xs[32 * 136];
    const int t = threadIdx.x, lane = t & 63, w = t >> 6, lr = lane & 15, lg = lane >> 4;
    const int n0 = blockIdx.x * 32;

    // stage 32 rows x 128 -> bf16 (rows >= NN read adjacent ws memory; stores guarded)
    for (int i = t; i < 1024; i += 256) {
        const int n = i >> 5, s4 = i & 31;
        const float4 xv = *(const float4*)(xin + (size_t)(n0 + n) * HD + s4 * 4);
        s16x4 hx;
        hx[0] = f2bf(xv.x); hx[1] = f2bf(xv.y); hx[2] = f2bf(xv.z); hx[3] = f2bf(xv.w);
        *(s16x4*)(xs + n * 136 + s4 * 4) = hx;
    }
    for (int i = t; i < 32 * ZD; i += 256) {
        const int n = i / ZD;
        if (n0 + n < NN) zbuf[(size_t)n0 * ZD + i] = 0.f;
    }
    __syncthreads();

    s16x8 wf[4][4];
#pragma unroll
    for (int nt = 0; nt < 4; nt++)
#pragma unroll
        for (int ks = 0; ks < 4; ks++)
            wf[nt][ks] = *(const s16x8*)(WAB + (size_t)(w * 64 + nt * 16 + lr) * HD + ks * 32 + lg * 8);

    f32x4 acc[2][4];
#pragma unroll
    for (int nt = 0; nt < 4; nt++) {
        const int cc = w * 64 + nt * 16 + lr;
        const float bb = (cc < 128) ? b0[cc] : 0.f;
        f32x4 v; v[0] = bb; v[1] = bb; v[2] = bb; v[3] = bb;
        acc[0][nt] = v;
        acc[1][nt] = v;
    }
#pragma unroll
    for (int ks = 0; ks < 4; ks++) {
#pragma unroll
        for (int g = 0; g < 2; g++) {
            const s16x8 xf = *(const s16x8*)(xs + (g * 16 + lr) * 136 + ks * 32 + lg * 8);
#pragma unroll
            for (int nt = 0; nt < 4; nt++)
                acc[g][nt] = __builtin_amdgcn_mfma_f32_16x16x32_bf16(xf, wf[nt][ks], acc[g][nt], 0, 0, 0);
        }
    }
#pragma unroll
    for (int g = 0; g < 2; g++)
#pragma unroll
        for (int nt = 0; nt < 4; nt++) {
            const int cc = w * 64 + nt * 16 + lr;
#pragma unroll
            for (int r = 0; r < 4; r++) {
                const int node = n0 + g * 16 + lg * 4 + r;
                if (node < NN) {
                    const ushort val = f2bf(acc[g][nt][r]);
                    if (cc < 128) A[(size_t)node * HD + cc] = val;
                    else Bm[(size_t)node * HD + (cc - 128)] = val;
                }
            }
        }
}

// ---------------- persistent MFMA edge kernel + cross-tile gather prefetch (R11/R12 winner) ----------------
// C/D frag: col = lane&15 (B-operand row), row = (lane>>4)*4 + reg (A-operand row)  [m89/m91]
template<int DOUTB>
__global__ __launch_bounds__(256, 2)
void edge_mfma_kernel(const ushort* __restrict__ Af, const ushort* __restrict__ Bf,
                      const ushort* __restrict__ W1T, const float* __restrict__ b1,
                      const ushort* __restrict__ W2T, const float* __restrict__ b2,
                      const int* __restrict__ ssrc, const int* __restrict__ nof,
                      float* __restrict__ out) {
    __shared__ __align__(16) ushort HH1[TILE * 136];   // h1 [e][k]; later m [c][e]
    __shared__ __align__(16) ushort HH2[TILE * 136];   // h2 [e][c]
    __shared__ __align__(16) int s_node[2][TILE];

    const int t = threadIdx.x;
    const int lane = t & 63;
    const int w = t >> 6;
    const int lr = lane & 15;
    const int lg = lane >> 4;
    const int cg = t & 15;      // gather k-chunk
    const int eb = t >> 4;      // gather base edge (e_i = eb + 16*i)

    // ---- persistent weight fragments (once per block) ----
    s16x8 w1f[2][4];
#pragma unroll
    for (int m = 0; m < 2; m++)
#pragma unroll
        for (int ks = 0; ks < 4; ks++)
            w1f[m][ks] = *(const s16x8*)(W1T + (size_t)(w * 32 + m * 16 + lr) * HD + ks * 32 + lg * 8);

    constexpr int CT3 = (DOUTB == 128) ? 2 : 1;
    s16x8 w2f[CT3][4];
#pragma unroll
    for (int ct = 0; ct < CT3; ct++) {
        const int row = (DOUTB == 128) ? ((w * 2 + ct) * 16 + lr) : lr;
#pragma unroll
        for (int ks = 0; ks < 4; ks++)
            w2f[ct][ks] = *(const s16x8*)(W2T + (size_t)row * HD + ks * 32 + lg * 8);
    }

    float bias2[2][4];
#pragma unroll
    for (int m = 0; m < 2; m++)
#pragma unroll
        for (int r = 0; r < 4; r++)
            bias2[m][r] = b1[w * 32 + m * 16 + lg * 4 + r];
    float bias3[CT3];
#pragma unroll
    for (int ct = 0; ct < CT3; ct++)
        bias3[ct] = (DOUTB == 128) ? b2[(w * 2 + ct) * 16 + lr] : b2[lr];

    // ---- prologue: tile-0 indices + bv gathers ----
    int tile = blockIdx.x;
    int ts = tile * TILE;
    if (t < TILE) s_node[0][t] = nof[ts + t];
    int nd[8], sr[8];
#pragma unroll
    for (int i = 0; i < 8; i++) {
        const int e = eb + 16 * i;
        nd[i] = nof[ts + e];
        sr[i] = ssrc[ts + e];
    }
    s16x8 bv[8];
#pragma unroll
    for (int i = 0; i < 8; i++)
        bv[i] = *(const s16x8*)(Bf + (size_t)sr[i] * HD + cg * 8);
    int buf = 0;
    __syncthreads();

    for (; tile < NTILES; tile += gridDim.x) {
        ts = tile * TILE;
        const int tn = (tile + (int)gridDim.x < NTILES) ? (tile + (int)gridDim.x) : tile;
        const int tsn = tn * TILE;

        // ---- h1 fill: av on demand (dst-sorted -> L1-hot), bv prefetched ----
#pragma unroll
        for (int i = 0; i < 8; i++) {
            const int e = eb + 16 * i;
            const s16x8 av = *(const s16x8*)(Af + (size_t)nd[i] * HD + cg * 8);
            s16x8 hv;
#pragma unroll
            for (int j = 0; j < 8; j++)
                hv[j] = f2bf(fmaxf(bf2f(av[j]) + bf2f(bv[i][j]), 0.f));
            *(s16x8*)(HH1 + e * 136 + cg * 8) = hv;
        }
        __syncthreads();

        // ---- prefetch next-tile indices + s_node[buf^1] (land during L2) ----
#pragma unroll
        for (int i = 0; i < 8; i++) {
            const int e = eb + 16 * i;
            nd[i] = nof[tsn + e];
            sr[i] = ssrc[tsn + e];
        }
        if (t < TILE) s_node[buf ^ 1][t] = nof[tsn + t];

        // ---- layer 2: D[c][e], wave's 32-c slice x ALL 128 edges ----
        f32x4 acc[2][8];
#pragma unroll
        for (int m = 0; m < 2; m++)
#pragma unroll
            for (int n = 0; n < 8; n++) {
                f32x4 v; v[0] = bias2[m][0]; v[1] = bias2[m][1]; v[2] = bias2[m][2]; v[3] = bias2[m][3];
                acc[m][n] = v;
            }
#pragma unroll
        for (int ks = 0; ks < 4; ks++) {
            const int k0 = ks * 32 + lg * 8;
            s16x8 bfr[8];
#pragma unroll
            for (int n = 0; n < 8; n++)
                bfr[n] = *(const s16x8*)(HH1 + (n * 16 + lr) * 136 + k0);
#pragma unroll
            for (int m = 0; m < 2; m++)
#pragma unroll
                for (int n = 0; n < 8; n++)
                    acc[m][n] = __builtin_amdgcn_mfma_f32_16x16x32_bf16(w1f[m][ks], bfr[n], acc[m][n], 0, 0, 0);
        }
        // h2 = relu(acc) -> HH2[e][c]
#pragma unroll
        for (int m = 0; m < 2; m++)
#pragma unroll
            for (int n = 0; n < 8; n++) {
                const int e = n * 16 + lr;
                const int c0 = w * 32 + m * 16 + lg * 4;
                s16x4 hv;
                hv[0] = f2bf(fmaxf(acc[m][n][0], 0.f));
                hv[1] = f2bf(fmaxf(acc[m][n][1], 0.f));
                hv[2] = f2bf(fmaxf(acc[m][n][2], 0.f));
                hv[3] = f2bf(fmaxf(acc[m][n][3], 0.f));
                *(s16x4*)(HH2 + e * 136 + c0) = hv;
            }
        // ---- issue next-tile bv gathers (land during L3+agg) ----
#pragma unroll
        for (int i = 0; i < 8; i++)
            bv[i] = *(const s16x8*)(Bf + (size_t)sr[i] * HD + cg * 8);
        __syncthreads();   // h2 visible; all HH1 reads retired

        // ---- layer 3 (swapped operands): D[e][c]; m -> HH1 ----
        if constexpr (DOUTB == 128) {
            f32x4 acc3[8][2];
#pragma unroll
            for (int n = 0; n < 8; n++)
#pragma unroll
                for (int ct = 0; ct < 2; ct++) {
                    const float bb = bias3[ct];
                    f32x4 v; v[0] = bb; v[1] = bb; v[2] = bb; v[3] = bb;
                    acc3[n][ct] = v;
                }
#pragma unroll
            for (int ks = 0; ks < 4; ks++) {
                const int k0 = ks * 32 + lg * 8;
                s16x8 h2f[8];
#pragma unroll
                for (int n = 0; n < 8; n++)
                    h2f[n] = *(const s16x8*)(HH2 + (n * 16 + lr) * 136 + k0);
#pragma unroll
                for (int n = 0; n < 8; n++)
#pragma unroll
                    for (int ct = 0; ct < 2; ct++)
                        acc3[n][ct] = __builtin_amdgcn_mfma_f32_16x16x32_bf16(h2f[n], w2f[ct][ks], acc3[n][ct], 0, 0, 0);
            }
#pragma unroll
            for (int n = 0; n < 8; n++)
#pragma unroll
                for (int ct = 0; ct < 2; ct++) {
                    const int e0 = n * 16 + lg * 4;
                    const int c = (w * 2 + ct) * 16 + lr;
                    s16x4 mv;
                    mv[0] = f2bf(acc3[n][ct][0]);
                    mv[1] = f2bf(acc3[n][ct][1]);
                    mv[2] = f2bf(acc3[n][ct][2]);
                    mv[3] = f2bf(acc3[n][ct][3]);
                    *(s16x4*)(HH1 + c * 136 + e0) = mv;
                }
        } else {
            f32x4 acc3[2];
#pragma unroll
            for (int e2 = 0; e2 < 2; e2++) {
                const float bb = bias3[0];
                f32x4 v; v[0] = bb; v[1] = bb; v[2] = bb; v[3] = bb;
                acc3[e2] = v;
            }
#pragma unroll
            for (int ks = 0; ks < 4; ks++) {
                const int k0 = ks * 32 + lg * 8;
#pragma unroll
                for (int e2 = 0; e2 < 2; e2++) {
                    const s16x8 h2f = *(const s16x8*)(HH2 + ((w * 2 + e2) * 16 + lr) * 136 + k0);
                    acc3[e2] = __builtin_amdgcn_mfma_f32_16x16x32_bf16(h2f, w2f[0][ks], acc3[e2], 0, 0, 0);
                }
            }
#pragma unroll
            for (int e2 = 0; e2 < 2; e2++) {
                const int e0 = (w * 2 + e2) * 16 + lg * 4;
                const int c = lr;
                s16x4 mv;
                mv[0] = f2bf(acc3[e2][0]);
                mv[1] = f2bf(acc3[e2][1]);
                mv[2] = f2bf(acc3[e2][2]);
                mv[3] = f2bf(acc3[e2][3]);
                *(s16x4*)(HH1 + c * 136 + e0) = mv;
            }
        }
        __syncthreads();   // m visible

        // ---- aggregation via MFMA: out[slot][c] = Σ_e sel[slot][e] m[e][c] ----
        const int* sn = s_node[buf];
        const int nd0 = sn[0];
        const int ndL = sn[TILE - 1];
        if constexpr (DOUTB == 128) {
            if (ndL - nd0 <= 15) {
                f32x4 agg[2];
                agg[0] = (f32x4)0.f; agg[1] = (f32x4)0.f;
#pragma unroll
                for (int ks = 0; ks < 4; ks++) {
                    const int4 na = *(const int4*)&sn[ks * 32 + lg * 8];
                    const int4 nb = *(const int4*)&sn[ks * 32 + lg * 8 + 4];
                    s16x8 sel;
                    sel[0] = (na.x - nd0 == lr) ? (short)0x3F80 : (short)0;
                    sel[1] = (na.y - nd0 == lr) ? (short)0x3F80 : (short)0;
                    sel[2] = (na.z - nd0 == lr) ? (short)0x3F80 : (short)0;
                    sel[3] = (na.w - nd0 == lr) ? (short)0x3F80 : (short)0;
                    sel[4] = (nb.x - nd0 == lr) ? (short)0x3F80 : (short)0;
                    sel[5] = (nb.y - nd0 == lr) ? (short)0x3F80 : (short)0;
                    sel[6] = (nb.z - nd0 == lr) ? (short)0x3F80 : (short)0;
                    sel[7] = (nb.w - nd0 == lr) ? (short)0x3F80 : (short)0;
#pragma unroll
                    for (int ci = 0; ci < 2; ci++) {
                        const s16x8 mf = *(const s16x8*)(HH1 + ((w * 2 + ci) * 16 + lr) * 136 + ks * 32 + lg * 8);
                        agg[ci] = __builtin_amdgcn_mfma_f32_16x16x32_bf16(sel, mf, agg[ci], 0, 0, 0);
                    }
                }
#pragma unroll
                for (int ci = 0; ci < 2; ci++) {
                    const int c = (w * 2 + ci) * 16 + lr;
#pragma unroll
                    for (int r = 0; r < 4; r++) {
                        const int ndn = nd0 + lg * 4 + r;
                        if (ndn <= ndL) {
                            float* dp = out + (size_t)ndn * 128 + c;
                            const float v = agg[ci][r];
                            if (ndn > nd0 && ndn < ndL) *dp = v;
                            else atomicAdd(dp, v);
                        }
                    }
                }
            } else {
                for (int idx = t; idx < TILE * 128; idx += 256) {
                    const int e = idx >> 7, c = idx & 127;
                    atomicAdd(out + (size_t)sn[e] * 128 + c, bf2f(HH1[c * 136 + e]));
                }
            }
        } else {
            const int nw0 = sn[w * 32];
            const int nwL = sn[w * 32 + 31];
            if (nwL - nw0 <= 15) {
                const int4 na = *(const int4*)&sn[w * 32 + lg * 8];
                const int4 nb = *(const int4*)&sn[w * 32 + lg * 8 + 4];
                s16x8 sel;
                sel[0] = (na.x - nw0 == lr) ? (short)0x3F80 : (short)0;
                sel[1] = (na.y - nw0 == lr) ? (short)0x3F80 : (short)0;
                sel[2] = (na.z - nw0 == lr) ? (short)0x3F80 : (short)0;
                sel[3] = (na.w - nw0 == lr) ? (short)0x3F80 : (short)0;
                sel[4] = (nb.x - nw0 == lr) ? (short)0x3F80 : (short)0;
                sel[5] = (nb.y - nw0 == lr) ? (short)0x3F80 : (short)0;
                sel[6] = (nb.z - nw0 == lr) ? (short)0x3F80 : (short)0;
                sel[7] = (nb.w - nw0 == lr) ? (short)0x3F80 : (short)0;
                const s16x8 mf = *(const s16x8*)(HH1 + lr * 136 + w * 32 + lg * 8);
                f32x4 agg = (f32x4)0.f;
                agg = __builtin_amdgcn_mfma_f32_16x16x32_bf16(sel, mf, agg, 0, 0, 0);
#pragma unroll
                for (int r = 0; r < 4; r++) {
                    const int ndn = nw0 + lg * 4 + r;
                    if (ndn <= nwL) {
                        float* dp = out + (size_t)ndn * 16 + lr;
                        const float v = agg[r];
                        if (ndn > nw0 && ndn < nwL) *dp = v;
                        else atomicAdd(dp, v);
                    }
                }
            } else {
                for (int idx = lane; idx < 32 * 16; idx += 64) {
                    const int e = w * 32 + (idx >> 4), c = idx & 15;
                    atomicAdd(out + (size_t)sn[e] * 16 + c, bf2f(HH1[c * 136 + e]));
                }
            }
        }
        buf ^= 1;
        __syncthreads();   // agg reads retired before next h1 fill
    }
}

extern "C" void kernel_launch(void* const* d_in, const int* in_sizes, int n_in,
                              void* d_out, int out_size, void* d_ws, size_t ws_size,
                              hipStream_t stream) {
    const float* x = (const float*)d_in[0];
    const int* ei = (const int*)d_in[2];
    const int* src = ei;
    const int* dst = ei + NE;
    const float* W[4][3];
    const float* bs[4][3];
    for (int b = 0; b < 4; b++)
        for (int l = 0; l < 3; l++) {
            W[b][l]  = (const float*)d_in[4 + b * 6 + l * 2];
            bs[b][l] = (const float*)d_in[4 + b * 6 + l * 2 + 1];
        }

    float* x0   = (float*)d_ws;
    float* x1   = x0 + (size_t)NN * HD;
    ushort* A   = (ushort*)(x1 + (size_t)NN * HD);
    ushort* Bm  = A + (size_t)NN * HD;
    ushort* WT  = Bm + (size_t)NN * HD;       // 229376 ushort = 448 KB
    int* cnt    = (int*)(WT + 229376);
    int* rs     = cnt + NN;
    int* cur    = rs + NN + 1;
    int* ssrc   = cur + NN;
    int* nof    = ssrc + NE;
    float* out  = (float*)d_out;

    WPtrs wp;
    for (int b = 0; b < 4; b++) { wp.w[2 * b] = W[b][1]; wp.w[2 * b + 1] = W[b][2]; }
    for (int b = 1; b < 4; b++) wp.w0[b - 1] = W[b][0];

    // fused prep: nodeAB block-0 + weight prep + cnt zero (all independent)
    prep_kernel<<<1505, 256, 0, stream>>>(x, W[0][0], bs[0][0], A, Bm, x0, wp, WT, cnt);
    hist_kernel<<<(NE + 255) / 256, 256, 0, stream>>>(dst, cnt);
    scan_kernel<<<1, 256, 0, stream>>>(cnt, rs, cur);
    scatter_kernel<<<(NE + 255) / 256, 256, 0, stream>>>(src, dst, cur, ssrc, nof);

    const ushort* W1T[4];
    const ushort* W2T[4];
    const ushort* WAB[4];
    for (int b = 0; b < 4; b++) { W1T[b] = WT + b * 16384; W2T[b] = WT + 65536 + b * 16384; }
    for (int b = 1; b < 4; b++) WAB[b] = WT + 131072 + (b - 1) * 32768;

    const int EG = 500;   // 2500 tiles / 500 blocks = exactly 5 tiles/block, 2 blocks/CU

    // block 0 (A,Bm and x0-zero done by prep)
    edge_mfma_kernel<128><<<EG, 256, 0, stream>>>(A, Bm, W1T[0], bs[0][1], W2T[0], bs[0][2], ssrc, nof, x0);
    // block 1 (MFMA layer-1, zeroes x1)
    nodeAB_mfma_kernel<<<(NN + 31) / 32, 256, 0, stream>>>(x0, WAB[1], bs[1][0], A, Bm, x1, 128);
    edge_mfma_kernel<128><<<EG, 256, 0, stream>>>(A, Bm, W1T[1], bs[1][1], W2T[1], bs[1][2], ssrc, nof, x1);
    // block 2 (zeroes x0)
    nodeAB_mfma_kernel<<<(NN + 31) / 32, 256, 0, stream>>>(x1, WAB[2], bs[2][0], A, Bm, x0, 128);
    edge_mfma_kernel<128><<<EG, 256, 0, stream>>>(A, Bm, W1T[2], bs[2][1], W2T[2], bs[2][2], ssrc, nof, x0);
    // block 3 (zeroes out) -> d_out
    nodeAB_mfma_kernel<<<(NN + 31) / 32, 256, 0, stream>>>(x0, WAB[3], bs[3][0], A, Bm, out, 16);
    edge_mfma_kernel<16><<<EG, 256, 0, stream>>>(A, Bm, W1T[3], bs[3][1], W2T[3], bs[3][2], ssrc, nof, out);
}